// Round 2
// baseline (429.448 us; speedup 1.0000x reference)
//
#include <hip/hip_runtime.h>

#define B_ 4
#define S_ 4096
#define E_ 2048
#define H_ 128

using f32x4 = __attribute__((ext_vector_type(4))) float;
using s16x8 = __attribute__((ext_vector_type(8))) short;
using s16x4 = __attribute__((ext_vector_type(4))) short;

// fp32 -> bf16 bits, round-to-nearest-even
__device__ __forceinline__ short f2bf(float f) {
  unsigned u = __float_as_uint(f);
  u += 0x7FFFu + ((u >> 16) & 1u);
  return (short)(u >> 16);
}

// 16-lane (row) rotate via DPP: VALU-speed cross-lane, no DS pipe.
template <int CTRL>
__device__ __forceinline__ float dpp_rot(float v) {
  return __int_as_float(__builtin_amdgcn_update_dpp(
      0, __float_as_int(v), CTRL, 0xF, 0xF, false));
}
__device__ __forceinline__ float rowmax16(float v) {
  v = fmaxf(v, dpp_rot<0x128>(v));  // ror 8
  v = fmaxf(v, dpp_rot<0x124>(v));  // ror 4
  v = fmaxf(v, dpp_rot<0x122>(v));  // ror 2
  v = fmaxf(v, dpp_rot<0x121>(v));  // ror 1
  return v;
}
__device__ __forceinline__ float rowsum16(float v) {
  v += dpp_rot<0x128>(v);
  v += dpp_rot<0x124>(v);
  v += dpp_rot<0x122>(v);
  v += dpp_rot<0x121>(v);
  return v;
}

// ---------------------------------------------------------------------------
// Kernel 1: W (E x H fp32) x3 -> Wt (384 x 2048 bf16) via LDS tile transpose.
// ---------------------------------------------------------------------------
__global__ __launch_bounds__(256) void prep_weights(
    const float* __restrict__ Wq, const float* __restrict__ Wk,
    const float* __restrict__ Wv, short* __restrict__ Wt) {
  __shared__ float T[32 * 33];
  int p = blockIdx.y;
  const float* W = (p == 0) ? Wq : ((p == 1) ? Wk : Wv);
  int e0 = (blockIdx.x & 63) * 32;
  int h0 = (blockIdx.x >> 6) * 32;
  int r = threadIdx.x >> 5;
  int c = threadIdx.x & 31;
#pragma unroll
  for (int i = 0; i < 4; ++i) {
    int e = r + 8 * i;
    T[c * 33 + e] = W[(size_t)(e0 + e) * H_ + h0 + c];
  }
  __syncthreads();
#pragma unroll
  for (int i = 0; i < 4; ++i) {
    int h = r + 8 * i;
    Wt[(size_t)(p * H_ + h0 + h) * E_ + e0 + c] = f2bf(T[h * 33 + c]);
  }
}

// ---------------------------------------------------------------------------
// Kernel 2: fused QKV projection GEMM, BK=64 (chunked XCD swizzle retained).
// ---------------------------------------------------------------------------
__global__ __launch_bounds__(256) void qkv_gemm(
    const float* __restrict__ x, const short* __restrict__ Wt,
    const float* __restrict__ bq, const float* __restrict__ bk,
    const float* __restrict__ bv,
    short* __restrict__ Q, short* __restrict__ K, short* __restrict__ Vt) {
  __shared__ __attribute__((aligned(16))) short xa[32 * 72];
  __shared__ __attribute__((aligned(16))) short wb[192 * 72];

  const int tid = threadIdx.x;
  const int wave = tid >> 6;
  const int lane = tid & 63;
  const int l15 = lane & 15;
  const int quad = lane >> 4;
  const int bidx = (int)blockIdx.x;
  const int lb = (bidx & 7) * 128 + (bidx >> 3);  // bijective, grid=1024
  const int row0 = (lb >> 1) * 32;
  const int nc0 = (lb & 1) * 192;

  f32x4 acc[2][3];
#pragma unroll
  for (int mg = 0; mg < 2; ++mg)
#pragma unroll
    for (int nt = 0; nt < 3; ++nt) acc[mg][nt] = (f32x4){0.f, 0.f, 0.f, 0.f};

  const int sr = tid >> 3;
  const int sc8 = (tid & 7) * 8;
  const int wr = tid >> 2;
  const int wo = (tid & 3) * 16;
  const float* xp = x + (size_t)(row0 + sr) * E_ + sc8;
  const short* wp = Wt + (size_t)(nc0 + wr) * E_ + wo;

  float4 xf0 = *(const float4*)(xp);
  float4 xf1 = *(const float4*)(xp + 4);
  s16x8 wreg[6];
#pragma unroll
  for (int j = 0; j < 3; ++j) {
    wreg[2 * j]     = *(const s16x8*)(wp + (size_t)(64 * j) * E_);
    wreg[2 * j + 1] = *(const s16x8*)(wp + (size_t)(64 * j) * E_ + 8);
  }

  for (int it = 0; it < 32; ++it) {
    __syncthreads();
    {
      s16x8 xv;
      xv[0] = f2bf(xf0.x); xv[1] = f2bf(xf0.y); xv[2] = f2bf(xf0.z); xv[3] = f2bf(xf0.w);
      xv[4] = f2bf(xf1.x); xv[5] = f2bf(xf1.y); xv[6] = f2bf(xf1.z); xv[7] = f2bf(xf1.w);
      *(s16x8*)&xa[sr * 72 + sc8] = xv;
    }
#pragma unroll
    for (int j = 0; j < 3; ++j) {
      *(s16x8*)&wb[(wr + 64 * j) * 72 + wo] = wreg[2 * j];
      *(s16x8*)&wb[(wr + 64 * j) * 72 + wo + 8] = wreg[2 * j + 1];
    }
    __syncthreads();

    if (it < 31) {
      const int k0n = (it + 1) * 64;
      xf0 = *(const float4*)(xp + k0n);
      xf1 = *(const float4*)(xp + k0n + 4);
#pragma unroll
      for (int j = 0; j < 3; ++j) {
        wreg[2 * j]     = *(const s16x8*)(wp + (size_t)(64 * j) * E_ + k0n);
        wreg[2 * j + 1] = *(const s16x8*)(wp + (size_t)(64 * j) * E_ + k0n + 8);
      }
    }

#pragma unroll
    for (int kc = 0; kc < 2; ++kc) {
      const int ko = kc * 32 + quad * 8;
      s16x8 af[2], bfr[3];
#pragma unroll
      for (int mg = 0; mg < 2; ++mg)
        af[mg] = *(const s16x8*)&xa[(mg * 16 + l15) * 72 + ko];
#pragma unroll
      for (int nt = 0; nt < 3; ++nt)
        bfr[nt] = *(const s16x8*)&wb[(wave * 48 + nt * 16 + l15) * 72 + ko];
#pragma unroll
      for (int mg = 0; mg < 2; ++mg)
#pragma unroll
        for (int nt = 0; nt < 3; ++nt)
          acc[mg][nt] = __builtin_amdgcn_mfma_f32_16x16x32_bf16(
              af[mg], bfr[nt], acc[mg][nt], 0, 0, 0);
    }
  }

  const float scale = 0.08838834764831845f;  // 1/sqrt(128), folded into Q
  const int b = row0 >> 12;
  const int s_base = row0 & (S_ - 1);
#pragma unroll
  for (int nt = 0; nt < 3; ++nt) {
    int col = nc0 + wave * 48 + nt * 16 + l15;
    int p = col >> 7;
    int h = col & (H_ - 1);
    if (p == 2) {
      float bsv = bv[h];
#pragma unroll
      for (int mg = 0; mg < 2; ++mg) {
        int s0 = s_base + mg * 16 + quad * 4;
        s16x4 vv;
#pragma unroll
        for (int r = 0; r < 4; ++r) vv[r] = f2bf(acc[mg][nt][r] + bsv);
        *(s16x4*)&Vt[((size_t)b * H_ + h) * S_ + s0] = vv;
      }
    } else if (p == 0) {
      float bsv = bq[h];
#pragma unroll
      for (int mg = 0; mg < 2; ++mg)
#pragma unroll
        for (int r = 0; r < 4; ++r) {
          int row = row0 + mg * 16 + quad * 4 + r;
          Q[(size_t)row * H_ + h] = f2bf((acc[mg][nt][r] + bsv) * scale);
        }
    } else {
      float bsv = bk[h];
#pragma unroll
      for (int mg = 0; mg < 2; ++mg)
#pragma unroll
        for (int r = 0; r < 4; ++r) {
          int row = row0 + mg * 16 + quad * 4 + r;
          K[(size_t)row * H_ + h] = f2bf(acc[mg][nt][r] + bsv);
        }
    }
  }
}

// ---------------------------------------------------------------------------
// Kernel 3: causal flash attention. R8 restructure, attacking the measured
// ~34,000-cycle wall time per wave-iteration (92% stall; MfmaUtil 5%):
//  (a) __launch_bounds__(512, 4): previous build allocated 60 VGPR against
//      ~90 of live state (compiler's 8-wave heuristic) -> per-iteration
//      spill/remat on the critical path. 4 waves/EU budget = 128 VGPR,
//      spill-free (~112 natural).
//  (b) Pair-tile blocks: each block processes q-tiles t = 255-slot THEN
//      t = slot. nk(t1)+nk(t2) is constant -> every wave in the grid does
//      an identical ~8-9 k-iterations. Grid 512 x 512thr = 2 blocks/CU,
//      16 waves/CU FLAT (old: per-CU work spread 1.65x, tail at 1-2
//      waves/SIMD caused the 42%-avg decaying occupancy).
//  (c) Split V-register hoist: V loads were trapped below the "memory"
//      clobber lgkmcnt asm, exposing full L2 latency after softmax. Now
//      nt=0..3 issue before softmax, nt=4..7 right after P-writes, so PV
//      never waits on memory.
// Batch->XCD pinning retained (b = (bid&7)>>1).
// ---------------------------------------------------------------------------
__global__ __launch_bounds__(512, 4) void flash_attn(
    const short* __restrict__ Qb, const short* __restrict__ Kb,
    const short* __restrict__ Vtb, float* __restrict__ out) {
  __shared__ __attribute__((aligned(16))) short p_all[8 * 16 * 72];  // 18432 B
  __shared__ float Ob[8 * 16 * 33];                                  // 16896 B
  __shared__ float mlds[128], llds[128];                             //  1024 B

  const int tid = threadIdx.x;
  const int w = tid >> 6;
  const int lane = tid & 63;
  const int l15 = lane & 15;
  const int quad = lane >> 4;
  const int bid = (int)blockIdx.x;
  const int xcd = bid & 7;
  const int b = xcd >> 1;                          // batch pinned to XCD pair
  const int slot = ((bid >> 3) << 1) | (xcd & 1);  // 0..127, bijective
  const size_t bo = (size_t)b * S_ * H_;
  const short* Vb = Vtb + (size_t)b * H_ * S_;     // [h][s]
  const float L2E = 1.4426950408889634f;
  short* p_lds = &p_all[w * (16 * 72)];

#pragma unroll 1
  for (int pp = 0; pp < 2; ++pp) {
    const int t = pp ? slot : (255 - slot);  // heavy tile first
    const int q0 = t * 16;
    const int nk = (t >> 2) + 1;  // 64-key tiles covering causal range

    s16x8 aq[4];
#pragma unroll
    for (int kt = 0; kt < 4; ++kt)
      aq[kt] = *(const s16x8*)(Qb + bo + (size_t)(q0 + l15) * H_ + kt * 32 + quad * 8);

    f32x4 oacc[8];
#pragma unroll
    for (int nt = 0; nt < 8; ++nt) oacc[nt] = (f32x4){0.f, 0.f, 0.f, 0.f};
    float m_r[4], l_r[4];
#pragma unroll
    for (int r = 0; r < 4; ++r) { m_r[r] = -3.0e38f; l_r[r] = 0.f; }

    for (int i = w; i < nk; i += 8) {
      const int kb = i * 64;
      // scores S = Q @ K^T (16 x 64), Q pre-scaled
      f32x4 sc[4];
#pragma unroll
      for (int nt = 0; nt < 4; ++nt) {
        f32x4 a = (f32x4){0.f, 0.f, 0.f, 0.f};
        const short* kp = Kb + bo + (size_t)(kb + nt * 16 + l15) * H_ + quad * 8;
#pragma unroll
        for (int kt = 0; kt < 4; ++kt)
          a = __builtin_amdgcn_mfma_f32_16x16x32_bf16(
              aq[kt], *(const s16x8*)(kp + kt * 32), a, 0, 0, 0);
        sc[nt] = a;
      }

      // V prefetch, first half (nt=0..3): overlaps softmax with L2 latency
      s16x8 va[8];
#pragma unroll
      for (int nt = 0; nt < 4; ++nt) {
        const short* vp = Vb + (size_t)(nt * 16 + l15) * S_ + kb + quad * 8;
        va[2 * nt]     = *(const s16x8*)(vp);
        va[2 * nt + 1] = *(const s16x8*)(vp + 32);
      }

      if (i == nk - 1) {  // diagonal k-tile: causal mask
        const int qloc = (t & 3) * 16 + quad * 4;
#pragma unroll
        for (int nt = 0; nt < 4; ++nt)
#pragma unroll
          for (int r = 0; r < 4; ++r)
            if (nt * 16 + l15 > qloc + r) sc[nt][r] = -3.0e38f;
      }
      // row max over 64 cols: 4 in-register + DPP 16-lane butterfly
      float vm[4], al[4], rs[4];
#pragma unroll
      for (int r = 0; r < 4; ++r) {
        vm[r] = rowmax16(
            fmaxf(fmaxf(sc[0][r], sc[1][r]), fmaxf(sc[2][r], sc[3][r])));
        float mn = fmaxf(m_r[r], vm[r]);
        al[r] = exp2f((m_r[r] - mn) * L2E);
        m_r[r] = mn;
      }
#pragma unroll
      for (int r = 0; r < 4; ++r) {
        float s = 0.f;
#pragma unroll
        for (int nt = 0; nt < 4; ++nt) {
          float pv = exp2f((sc[nt][r] - m_r[r]) * L2E);
          sc[nt][r] = pv;
          s += pv;
        }
        rs[r] = rowsum16(s);
        l_r[r] = l_r[r] * al[r] + rs[r];
      }

      // P (C-layout) -> per-wave LDS (bf16, A-layout read below)
      __asm__ volatile("s_waitcnt lgkmcnt(0)" ::: "memory");  // WAR vs prior reads
#pragma unroll
      for (int nt = 0; nt < 4; ++nt)
#pragma unroll
        for (int r = 0; r < 4; ++r)
          p_lds[(quad * 4 + r) * 72 + nt * 16 + l15] = f2bf(sc[nt][r]);

      // V prefetch, second half (nt=4..7): in flight during rescale + PV(0..3)
      s16x8 vb2[8];
#pragma unroll
      for (int nt = 0; nt < 4; ++nt) {
        const short* vp = Vb + (size_t)((nt + 4) * 16 + l15) * S_ + kb + quad * 8;
        vb2[2 * nt]     = *(const s16x8*)(vp);
        vb2[2 * nt + 1] = *(const s16x8*)(vp + 32);
      }

      // rescale O while the LDS writes land
#pragma unroll
      for (int nt = 0; nt < 8; ++nt)
#pragma unroll
        for (int r = 0; r < 4; ++r) oacc[nt][r] *= al[r];

      __asm__ volatile("s_waitcnt lgkmcnt(0)" ::: "memory");  // RAW: writes visible
      s16x8 ap[2];
#pragma unroll
      for (int kt2 = 0; kt2 < 2; ++kt2)
        ap[kt2] = *(const s16x8*)&p_lds[l15 * 72 + kt2 * 32 + quad * 8];

      // O += P @ V (V already in registers)
#pragma unroll
      for (int nt = 0; nt < 4; ++nt) {
        oacc[nt] = __builtin_amdgcn_mfma_f32_16x16x32_bf16(
            ap[0], va[2 * nt], oacc[nt], 0, 0, 0);
        oacc[nt] = __builtin_amdgcn_mfma_f32_16x16x32_bf16(
            ap[1], va[2 * nt + 1], oacc[nt], 0, 0, 0);
      }
#pragma unroll
      for (int nt = 0; nt < 4; ++nt) {
        oacc[nt + 4] = __builtin_amdgcn_mfma_f32_16x16x32_bf16(
            ap[0], vb2[2 * nt], oacc[nt + 4], 0, 0, 0);
        oacc[nt + 4] = __builtin_amdgcn_mfma_f32_16x16x32_bf16(
            ap[1], vb2[2 * nt + 1], oacc[nt + 4], 0, 0, 0);
      }
    }

    // ---- 8-way cross-wave merge, chunked 32 cols at a time ----
    if (l15 == 0) {
#pragma unroll
      for (int r = 0; r < 4; ++r) {
        mlds[w * 16 + quad * 4 + r] = m_r[r];
        llds[w * 16 + quad * 4 + r] = l_r[r];
      }
    }
    __syncthreads();

    const int row = tid >> 5;   // 0..15
    const int col = tid & 31;   // 0..31
    float mw[8];
#pragma unroll
    for (int w2 = 0; w2 < 8; ++w2) mw[w2] = mlds[w2 * 16 + row];
    float ms = mw[0];
#pragma unroll
    for (int w2 = 1; w2 < 8; ++w2) ms = fmaxf(ms, mw[w2]);
    float fw[8], lf = 0.f;
#pragma unroll
    for (int w2 = 0; w2 < 8; ++w2) {
      fw[w2] = exp2f((mw[w2] - ms) * L2E);
      lf += fw[w2] * llds[w2 * 16 + row];
    }
    const float invl = 1.0f / lf;

#pragma unroll
    for (int c = 0; c < 4; ++c) {
#pragma unroll
      for (int j = 0; j < 2; ++j) {
        int nt = 2 * c + j;
#pragma unroll
        for (int r = 0; r < 4; ++r)
          Ob[(w * 16 + quad * 4 + r) * 33 + j * 16 + l15] = oacc[nt][r];
      }
      __syncthreads();
      float o = 0.f;
#pragma unroll
      for (int w2 = 0; w2 < 8; ++w2) o += fw[w2] * Ob[(w2 * 16 + row) * 33 + col];
      out[bo + (size_t)(q0 + row) * H_ + c * 32 + col] = o * invl;
      __syncthreads();  // buffer reused next chunk / next tile
    }
  }
}

// ---------------------------------------------------------------------------
extern "C" void kernel_launch(void* const* d_in, const int* in_sizes, int n_in,
                              void* d_out, int out_size, void* d_ws, size_t ws_size,
                              hipStream_t stream) {
  const float* x  = (const float*)d_in[0];
  const float* Wq = (const float*)d_in[1];
  const float* bq = (const float*)d_in[2];
  const float* Wk = (const float*)d_in[3];
  const float* bk = (const float*)d_in[4];
  const float* Wv = (const float*)d_in[5];
  const float* bv = (const float*)d_in[6];

  // ws layout: Wt (384*2048 bf16) | Q | K | Vt (each B*S*H bf16) ~= 13.5 MB
  short* Wt = (short*)d_ws;
  short* Q  = Wt + (size_t)384 * E_;
  short* K  = Q + (size_t)B_ * S_ * H_;
  short* Vt = K + (size_t)B_ * S_ * H_;
  float* out = (float*)d_out;

  hipLaunchKernelGGL(prep_weights, dim3(64 * 4, 3), dim3(256), 0, stream,
                     Wq, Wk, Wv, Wt);
  hipLaunchKernelGGL(qkv_gemm, dim3((B_ * S_) / 32 * 2), dim3(256), 0, stream,
                     x, Wt, bq, bk, bv, Q, K, Vt);
  // R8: pair-tile blocks — 512 blocks, each does q-tiles (255-slot, slot)
  hipLaunchKernelGGL(flash_attn, dim3((S_ / 16) * B_ / 2), dim3(512), 0, stream,
                     Q, K, Vt, out);
}

// Round 3
// 405.544 us; speedup vs baseline: 1.0589x; 1.0589x over previous
//
#include <hip/hip_runtime.h>

#define B_ 4
#define S_ 4096
#define E_ 2048
#define H_ 128

using f32x4 = __attribute__((ext_vector_type(4))) float;
using s16x8 = __attribute__((ext_vector_type(8))) short;
using s16x4 = __attribute__((ext_vector_type(4))) short;

// fp32 -> bf16 bits, round-to-nearest-even
__device__ __forceinline__ short f2bf(float f) {
  unsigned u = __float_as_uint(f);
  u += 0x7FFFu + ((u >> 16) & 1u);
  return (short)(u >> 16);
}

// 16-lane (row) rotate via DPP: VALU-speed cross-lane, no DS pipe.
template <int CTRL>
__device__ __forceinline__ float dpp_rot(float v) {
  return __int_as_float(__builtin_amdgcn_update_dpp(
      0, __float_as_int(v), CTRL, 0xF, 0xF, false));
}
__device__ __forceinline__ float rowmax16(float v) {
  v = fmaxf(v, dpp_rot<0x128>(v));  // ror 8
  v = fmaxf(v, dpp_rot<0x124>(v));  // ror 4
  v = fmaxf(v, dpp_rot<0x122>(v));  // ror 2
  v = fmaxf(v, dpp_rot<0x121>(v));  // ror 1
  return v;
}
__device__ __forceinline__ float rowsum16(float v) {
  v += dpp_rot<0x128>(v);
  v += dpp_rot<0x124>(v);
  v += dpp_rot<0x122>(v);
  v += dpp_rot<0x121>(v);
  return v;
}

// ---------------------------------------------------------------------------
// Kernel 1: W (E x H fp32) x3 -> Wt (384 x 2048 bf16) via LDS tile transpose.
// ---------------------------------------------------------------------------
__global__ __launch_bounds__(256) void prep_weights(
    const float* __restrict__ Wq, const float* __restrict__ Wk,
    const float* __restrict__ Wv, short* __restrict__ Wt) {
  __shared__ float T[32 * 33];
  int p = blockIdx.y;
  const float* W = (p == 0) ? Wq : ((p == 1) ? Wk : Wv);
  int e0 = (blockIdx.x & 63) * 32;
  int h0 = (blockIdx.x >> 6) * 32;
  int r = threadIdx.x >> 5;
  int c = threadIdx.x & 31;
#pragma unroll
  for (int i = 0; i < 4; ++i) {
    int e = r + 8 * i;
    T[c * 33 + e] = W[(size_t)(e0 + e) * H_ + h0 + c];
  }
  __syncthreads();
#pragma unroll
  for (int i = 0; i < 4; ++i) {
    int h = r + 8 * i;
    Wt[(size_t)(p * H_ + h0 + h) * E_ + e0 + c] = f2bf(T[h * 33 + c]);
  }
}

// ---------------------------------------------------------------------------
// Kernel 2: fused QKV projection GEMM, BK=64.
// R9: the W LDS round-trip (24 KB/iter global->reg->LDS->reg, each element
// read by exactly ONE wave = zero reuse) is deleted. Each wave now loads its
// own 48-col B-fragments directly global->register, double-buffered one
// k-step ahead (same access pattern as flash_attn's K loads; W panel is
// L2-resident). x keeps its LDS staging (genuine 4x cross-wave reuse).
// Removes ~2/3 of the DS traffic that made this kernel staging-bound
// (12 MFMA ~60cy vs ~28KB DS ~220cy per iter).
// ---------------------------------------------------------------------------
__global__ __launch_bounds__(256) void qkv_gemm(
    const float* __restrict__ x, const short* __restrict__ Wt,
    const float* __restrict__ bq, const float* __restrict__ bk,
    const float* __restrict__ bv,
    short* __restrict__ Q, short* __restrict__ K, short* __restrict__ Vt) {
  __shared__ __attribute__((aligned(16))) short xa[32 * 72];

  const int tid = threadIdx.x;
  const int wave = tid >> 6;
  const int lane = tid & 63;
  const int l15 = lane & 15;
  const int quad = lane >> 4;
  const int bidx = (int)blockIdx.x;
  const int lb = (bidx & 7) * 128 + (bidx >> 3);  // bijective, grid=1024
  const int row0 = (lb >> 1) * 32;
  const int nc0 = (lb & 1) * 192;

  f32x4 acc[2][3];
#pragma unroll
  for (int mg = 0; mg < 2; ++mg)
#pragma unroll
    for (int nt = 0; nt < 3; ++nt) acc[mg][nt] = (f32x4){0.f, 0.f, 0.f, 0.f};

  const int sr = tid >> 3;
  const int sc8 = (tid & 7) * 8;
  const float* xp = x + (size_t)(row0 + sr) * E_ + sc8;
  // per-wave B-fragment base: col = nc0 + wave*48 + nt*16 + l15, k = quad*8
  const short* wp = Wt + (size_t)(nc0 + wave * 48 + l15) * E_ + quad * 8;

  float4 xf0 = *(const float4*)(xp);
  float4 xf1 = *(const float4*)(xp + 4);
  s16x8 wreg[6];  // [nt][kc] fragments for current k-step
#pragma unroll
  for (int nt = 0; nt < 3; ++nt)
#pragma unroll
    for (int kc = 0; kc < 2; ++kc)
      wreg[nt * 2 + kc] =
          *(const s16x8*)(wp + (size_t)(nt * 16) * E_ + kc * 32);

  for (int it = 0; it < 32; ++it) {
    __syncthreads();  // WAR: xa rewrite vs prior reads
    {
      s16x8 xv;
      xv[0] = f2bf(xf0.x); xv[1] = f2bf(xf0.y); xv[2] = f2bf(xf0.z); xv[3] = f2bf(xf0.w);
      xv[4] = f2bf(xf1.x); xv[5] = f2bf(xf1.y); xv[6] = f2bf(xf1.z); xv[7] = f2bf(xf1.w);
      *(s16x8*)&xa[sr * 72 + sc8] = xv;
    }
    __syncthreads();

    s16x8 bcur[6];
#pragma unroll
    for (int j = 0; j < 6; ++j) bcur[j] = wreg[j];

    if (it < 31) {
      const int k0n = (it + 1) * 64;
      xf0 = *(const float4*)(xp + k0n);
      xf1 = *(const float4*)(xp + k0n + 4);
#pragma unroll
      for (int nt = 0; nt < 3; ++nt)
#pragma unroll
        for (int kc = 0; kc < 2; ++kc)
          wreg[nt * 2 + kc] =
              *(const s16x8*)(wp + (size_t)(nt * 16) * E_ + k0n + kc * 32);
    }

#pragma unroll
    for (int kc = 0; kc < 2; ++kc) {
      const int ko = kc * 32 + quad * 8;
      s16x8 af[2];
      af[0] = *(const s16x8*)&xa[l15 * 72 + ko];
      af[1] = *(const s16x8*)&xa[(16 + l15) * 72 + ko];
#pragma unroll
      for (int mg = 0; mg < 2; ++mg)
#pragma unroll
        for (int nt = 0; nt < 3; ++nt)
          acc[mg][nt] = __builtin_amdgcn_mfma_f32_16x16x32_bf16(
              af[mg], bcur[nt * 2 + kc], acc[mg][nt], 0, 0, 0);
    }
  }

  const float scale = 0.08838834764831845f;  // 1/sqrt(128), folded into Q
  const int b = row0 >> 12;
  const int s_base = row0 & (S_ - 1);
#pragma unroll
  for (int nt = 0; nt < 3; ++nt) {
    int col = nc0 + wave * 48 + nt * 16 + l15;
    int p = col >> 7;
    int h = col & (H_ - 1);
    if (p == 2) {
      float bsv = bv[h];
#pragma unroll
      for (int mg = 0; mg < 2; ++mg) {
        int s0 = s_base + mg * 16 + quad * 4;
        s16x4 vv;
#pragma unroll
        for (int r = 0; r < 4; ++r) vv[r] = f2bf(acc[mg][nt][r] + bsv);
        *(s16x4*)&Vt[((size_t)b * H_ + h) * S_ + s0] = vv;
      }
    } else if (p == 0) {
      float bsv = bq[h];
#pragma unroll
      for (int mg = 0; mg < 2; ++mg)
#pragma unroll
        for (int r = 0; r < 4; ++r) {
          int row = row0 + mg * 16 + quad * 4 + r;
          Q[(size_t)row * H_ + h] = f2bf((acc[mg][nt][r] + bsv) * scale);
        }
    } else {
      float bsv = bk[h];
#pragma unroll
      for (int mg = 0; mg < 2; ++mg)
#pragma unroll
        for (int r = 0; r < 4; ++r) {
          int row = row0 + mg * 16 + quad * 4 + r;
          K[(size_t)row * H_ + h] = f2bf(acc[mg][nt][r] + bsv);
        }
    }
  }
}

// ---------------------------------------------------------------------------
// Kernel 3: causal flash attention. R9 = R8 structure with the VGPR clamp
// FIXED: __launch_bounds__(512, 2). R8's (512,4) was interpreted as min
// 4 blocks/CU -> 8 waves/SIMD -> 64-VGPR clamp, which spilled the +64 VGPR
// of V-prefetch state to scratch (FETCH 10->105 MB, WRITE 8->181 MB, 178us).
// (512,2) -> 2 blocks/CU -> 128-VGPR budget; live peak ~120, spill-free.
//  (a) Pair-tile blocks: each block does q-tiles (255-slot, slot); constant
//      work -> 512 blocks, 2/CU, flat 16 waves/CU, no occupancy-decay tail.
//  (b) Split V-register hoist: nt=0..3 issued before softmax, nt=4..7 after
//      P-writes, so PV never waits on L2.
// Batch->XCD pinning retained.
// ---------------------------------------------------------------------------
__global__ __launch_bounds__(512, 2) void flash_attn(
    const short* __restrict__ Qb, const short* __restrict__ Kb,
    const short* __restrict__ Vtb, float* __restrict__ out) {
  __shared__ __attribute__((aligned(16))) short p_all[8 * 16 * 72];  // 18432 B
  __shared__ float Ob[8 * 16 * 33];                                  // 16896 B
  __shared__ float mlds[128], llds[128];                             //  1024 B

  const int tid = threadIdx.x;
  const int w = tid >> 6;
  const int lane = tid & 63;
  const int l15 = lane & 15;
  const int quad = lane >> 4;
  const int bid = (int)blockIdx.x;
  const int xcd = bid & 7;
  const int b = xcd >> 1;                          // batch pinned to XCD pair
  const int slot = ((bid >> 3) << 1) | (xcd & 1);  // 0..127, bijective
  const size_t bo = (size_t)b * S_ * H_;
  const short* Vb = Vtb + (size_t)b * H_ * S_;     // [h][s]
  const float L2E = 1.4426950408889634f;
  short* p_lds = &p_all[w * (16 * 72)];

#pragma unroll 1
  for (int pp = 0; pp < 2; ++pp) {
    const int t = pp ? slot : (255 - slot);  // heavy tile first
    const int q0 = t * 16;
    const int nk = (t >> 2) + 1;  // 64-key tiles covering causal range

    s16x8 aq[4];
#pragma unroll
    for (int kt = 0; kt < 4; ++kt)
      aq[kt] = *(const s16x8*)(Qb + bo + (size_t)(q0 + l15) * H_ + kt * 32 + quad * 8);

    f32x4 oacc[8];
#pragma unroll
    for (int nt = 0; nt < 8; ++nt) oacc[nt] = (f32x4){0.f, 0.f, 0.f, 0.f};
    float m_r[4], l_r[4];
#pragma unroll
    for (int r = 0; r < 4; ++r) { m_r[r] = -3.0e38f; l_r[r] = 0.f; }

    for (int i = w; i < nk; i += 8) {
      const int kb = i * 64;
      // scores S = Q @ K^T (16 x 64), Q pre-scaled
      f32x4 sc[4];
#pragma unroll
      for (int nt = 0; nt < 4; ++nt) {
        f32x4 a = (f32x4){0.f, 0.f, 0.f, 0.f};
        const short* kp = Kb + bo + (size_t)(kb + nt * 16 + l15) * H_ + quad * 8;
#pragma unroll
        for (int kt = 0; kt < 4; ++kt)
          a = __builtin_amdgcn_mfma_f32_16x16x32_bf16(
              aq[kt], *(const s16x8*)(kp + kt * 32), a, 0, 0, 0);
        sc[nt] = a;
      }

      // V prefetch, first half (nt=0..3): overlaps softmax with L2 latency
      s16x8 va[8];
#pragma unroll
      for (int nt = 0; nt < 4; ++nt) {
        const short* vp = Vb + (size_t)(nt * 16 + l15) * S_ + kb + quad * 8;
        va[2 * nt]     = *(const s16x8*)(vp);
        va[2 * nt + 1] = *(const s16x8*)(vp + 32);
      }

      if (i == nk - 1) {  // diagonal k-tile: causal mask
        const int qloc = (t & 3) * 16 + quad * 4;
#pragma unroll
        for (int nt = 0; nt < 4; ++nt)
#pragma unroll
          for (int r = 0; r < 4; ++r)
            if (nt * 16 + l15 > qloc + r) sc[nt][r] = -3.0e38f;
      }
      // row max over 64 cols: 4 in-register + DPP 16-lane butterfly
      float vm[4], al[4], rs[4];
#pragma unroll
      for (int r = 0; r < 4; ++r) {
        vm[r] = rowmax16(
            fmaxf(fmaxf(sc[0][r], sc[1][r]), fmaxf(sc[2][r], sc[3][r])));
        float mn = fmaxf(m_r[r], vm[r]);
        al[r] = exp2f((m_r[r] - mn) * L2E);
        m_r[r] = mn;
      }
#pragma unroll
      for (int r = 0; r < 4; ++r) {
        float s = 0.f;
#pragma unroll
        for (int nt = 0; nt < 4; ++nt) {
          float pv = exp2f((sc[nt][r] - m_r[r]) * L2E);
          sc[nt][r] = pv;
          s += pv;
        }
        rs[r] = rowsum16(s);
        l_r[r] = l_r[r] * al[r] + rs[r];
      }

      // P (C-layout) -> per-wave LDS (bf16, A-layout read below)
      __asm__ volatile("s_waitcnt lgkmcnt(0)" ::: "memory");  // WAR vs prior reads
#pragma unroll
      for (int nt = 0; nt < 4; ++nt)
#pragma unroll
        for (int r = 0; r < 4; ++r)
          p_lds[(quad * 4 + r) * 72 + nt * 16 + l15] = f2bf(sc[nt][r]);

      // V prefetch, second half (nt=4..7): in flight during rescale + PV(0..3)
      s16x8 vb2[8];
#pragma unroll
      for (int nt = 0; nt < 4; ++nt) {
        const short* vp = Vb + (size_t)((nt + 4) * 16 + l15) * S_ + kb + quad * 8;
        vb2[2 * nt]     = *(const s16x8*)(vp);
        vb2[2 * nt + 1] = *(const s16x8*)(vp + 32);
      }

      // rescale O while the LDS writes land
#pragma unroll
      for (int nt = 0; nt < 8; ++nt)
#pragma unroll
        for (int r = 0; r < 4; ++r) oacc[nt][r] *= al[r];

      __asm__ volatile("s_waitcnt lgkmcnt(0)" ::: "memory");  // RAW: writes visible
      s16x8 ap[2];
#pragma unroll
      for (int kt2 = 0; kt2 < 2; ++kt2)
        ap[kt2] = *(const s16x8*)&p_lds[l15 * 72 + kt2 * 32 + quad * 8];

      // O += P @ V (V already in registers)
#pragma unroll
      for (int nt = 0; nt < 4; ++nt) {
        oacc[nt] = __builtin_amdgcn_mfma_f32_16x16x32_bf16(
            ap[0], va[2 * nt], oacc[nt], 0, 0, 0);
        oacc[nt] = __builtin_amdgcn_mfma_f32_16x16x32_bf16(
            ap[1], va[2 * nt + 1], oacc[nt], 0, 0, 0);
      }
#pragma unroll
      for (int nt = 0; nt < 4; ++nt) {
        oacc[nt + 4] = __builtin_amdgcn_mfma_f32_16x16x32_bf16(
            ap[0], vb2[2 * nt], oacc[nt + 4], 0, 0, 0);
        oacc[nt + 4] = __builtin_amdgcn_mfma_f32_16x16x32_bf16(
            ap[1], vb2[2 * nt + 1], oacc[nt + 4], 0, 0, 0);
      }
    }

    // ---- 8-way cross-wave merge, chunked 32 cols at a time ----
    if (l15 == 0) {
#pragma unroll
      for (int r = 0; r < 4; ++r) {
        mlds[w * 16 + quad * 4 + r] = m_r[r];
        llds[w * 16 + quad * 4 + r] = l_r[r];
      }
    }
    __syncthreads();

    const int row = tid >> 5;   // 0..15
    const int col = tid & 31;   // 0..31
    float mw[8];
#pragma unroll
    for (int w2 = 0; w2 < 8; ++w2) mw[w2] = mlds[w2 * 16 + row];
    float ms = mw[0];
#pragma unroll
    for (int w2 = 1; w2 < 8; ++w2) ms = fmaxf(ms, mw[w2]);
    float fw[8], lf = 0.f;
#pragma unroll
    for (int w2 = 0; w2 < 8; ++w2) {
      fw[w2] = exp2f((mw[w2] - ms) * L2E);
      lf += fw[w2] * llds[w2 * 16 + row];
    }
    const float invl = 1.0f / lf;

#pragma unroll
    for (int c = 0; c < 4; ++c) {
#pragma unroll
      for (int j = 0; j < 2; ++j) {
        int nt = 2 * c + j;
#pragma unroll
        for (int r = 0; r < 4; ++r)
          Ob[(w * 16 + quad * 4 + r) * 33 + j * 16 + l15] = oacc[nt][r];
      }
      __syncthreads();
      float o = 0.f;
#pragma unroll
      for (int w2 = 0; w2 < 8; ++w2) o += fw[w2] * Ob[(w2 * 16 + row) * 33 + col];
      out[bo + (size_t)(q0 + row) * H_ + c * 32 + col] = o * invl;
      __syncthreads();  // buffer reused next chunk / next tile
    }
  }
}

// ---------------------------------------------------------------------------
extern "C" void kernel_launch(void* const* d_in, const int* in_sizes, int n_in,
                              void* d_out, int out_size, void* d_ws, size_t ws_size,
                              hipStream_t stream) {
  const float* x  = (const float*)d_in[0];
  const float* Wq = (const float*)d_in[1];
  const float* bq = (const float*)d_in[2];
  const float* Wk = (const float*)d_in[3];
  const float* bk = (const float*)d_in[4];
  const float* Wv = (const float*)d_in[5];
  const float* bv = (const float*)d_in[6];

  // ws layout: Wt (384*2048 bf16) | Q | K | Vt (each B*S*H bf16) ~= 13.5 MB
  short* Wt = (short*)d_ws;
  short* Q  = Wt + (size_t)384 * E_;
  short* K  = Q + (size_t)B_ * S_ * H_;
  short* Vt = K + (size_t)B_ * S_ * H_;
  float* out = (float*)d_out;

  hipLaunchKernelGGL(prep_weights, dim3(64 * 4, 3), dim3(256), 0, stream,
                     Wq, Wk, Wv, Wt);
  hipLaunchKernelGGL(qkv_gemm, dim3((B_ * S_) / 32 * 2), dim3(256), 0, stream,
                     x, Wt, bq, bk, bv, Q, K, Vt);
  // pair-tile blocks: 512 blocks, each does q-tiles (255-slot, slot)
  hipLaunchKernelGGL(flash_attn, dim3((S_ / 16) * B_ / 2), dim3(512), 0, stream,
                     Q, K, Vt, out);
}

// Round 4
// 378.023 us; speedup vs baseline: 1.1360x; 1.0728x over previous
//
#include <hip/hip_runtime.h>

#define B_ 4
#define S_ 4096
#define E_ 2048
#define H_ 128

using f32x4 = __attribute__((ext_vector_type(4))) float;
using s16x8 = __attribute__((ext_vector_type(8))) short;
using s16x4 = __attribute__((ext_vector_type(4))) short;

// fp32 -> bf16 bits, round-to-nearest-even
__device__ __forceinline__ short f2bf(float f) {
  unsigned u = __float_as_uint(f);
  u += 0x7FFFu + ((u >> 16) & 1u);
  return (short)(u >> 16);
}

// 16-lane (row) rotate via DPP: VALU-speed cross-lane, no DS pipe.
template <int CTRL>
__device__ __forceinline__ float dpp_rot(float v) {
  return __int_as_float(__builtin_amdgcn_update_dpp(
      0, __float_as_int(v), CTRL, 0xF, 0xF, false));
}
__device__ __forceinline__ float rowmax16(float v) {
  v = fmaxf(v, dpp_rot<0x128>(v));  // ror 8
  v = fmaxf(v, dpp_rot<0x124>(v));  // ror 4
  v = fmaxf(v, dpp_rot<0x122>(v));  // ror 2
  v = fmaxf(v, dpp_rot<0x121>(v));  // ror 1
  return v;
}
__device__ __forceinline__ float rowsum16(float v) {
  v += dpp_rot<0x128>(v);
  v += dpp_rot<0x124>(v);
  v += dpp_rot<0x122>(v);
  v += dpp_rot<0x121>(v);
  return v;
}

// async global(16B/lane, per-lane addr) -> LDS (wave-uniform base + lane*16)
__device__ __forceinline__ void gload_lds16(const void* g, void* l) {
  __builtin_amdgcn_global_load_lds(
      (const __attribute__((address_space(1))) void*)g,
      (__attribute__((address_space(3))) void*)l, 16, 0, 0);
}

// ---------------------------------------------------------------------------
// Kernel 1: W (E x H fp32) x3 -> Wt (384 x 2048 bf16) via LDS tile transpose.
// ---------------------------------------------------------------------------
__global__ __launch_bounds__(256) void prep_weights(
    const float* __restrict__ Wq, const float* __restrict__ Wk,
    const float* __restrict__ Wv, short* __restrict__ Wt) {
  __shared__ float T[32 * 33];
  int p = blockIdx.y;
  const float* W = (p == 0) ? Wq : ((p == 1) ? Wk : Wv);
  int e0 = (blockIdx.x & 63) * 32;
  int h0 = (blockIdx.x >> 6) * 32;
  int r = threadIdx.x >> 5;
  int c = threadIdx.x & 31;
#pragma unroll
  for (int i = 0; i < 4; ++i) {
    int e = r + 8 * i;
    T[c * 33 + e] = W[(size_t)(e0 + e) * H_ + h0 + c];
  }
  __syncthreads();
#pragma unroll
  for (int i = 0; i < 4; ++i) {
    int h = r + 8 * i;
    Wt[(size_t)(p * H_ + h0 + h) * E_ + e0 + c] = f2bf(T[h * 33 + c]);
  }
}

// ---------------------------------------------------------------------------
// Kernel 2: fused QKV projection GEMM, BK=64. R0 version restored verbatim:
// R9's per-wave direct W loads (4KB-strided, 16 lines/load) REGRESSED ~28us
// -- independent evidence that divergent per-lane global loads serialize.
// The wb LDS staging (coalesced global, LDS-shared) is the right structure.
// ---------------------------------------------------------------------------
__global__ __launch_bounds__(256) void qkv_gemm(
    const float* __restrict__ x, const short* __restrict__ Wt,
    const float* __restrict__ bq, const float* __restrict__ bk,
    const float* __restrict__ bv,
    short* __restrict__ Q, short* __restrict__ K, short* __restrict__ Vt) {
  __shared__ __attribute__((aligned(16))) short xa[32 * 72];
  __shared__ __attribute__((aligned(16))) short wb[192 * 72];

  const int tid = threadIdx.x;
  const int wave = tid >> 6;
  const int lane = tid & 63;
  const int l15 = lane & 15;
  const int quad = lane >> 4;
  const int row0 = (blockIdx.x >> 1) * 32;
  const int nc0 = (blockIdx.x & 1) * 192;

  f32x4 acc[2][3];
#pragma unroll
  for (int mg = 0; mg < 2; ++mg)
#pragma unroll
    for (int nt = 0; nt < 3; ++nt) acc[mg][nt] = (f32x4){0.f, 0.f, 0.f, 0.f};

  const int sr = tid >> 3;
  const int sc8 = (tid & 7) * 8;
  const int wr = tid >> 2;
  const int wo = (tid & 3) * 16;
  const float* xp = x + (size_t)(row0 + sr) * E_ + sc8;
  const short* wp = Wt + (size_t)(nc0 + wr) * E_ + wo;

  float4 xf0 = *(const float4*)(xp);
  float4 xf1 = *(const float4*)(xp + 4);
  s16x8 wreg[6];
#pragma unroll
  for (int j = 0; j < 3; ++j) {
    wreg[2 * j]     = *(const s16x8*)(wp + (size_t)(64 * j) * E_);
    wreg[2 * j + 1] = *(const s16x8*)(wp + (size_t)(64 * j) * E_ + 8);
  }

  for (int it = 0; it < 32; ++it) {
    __syncthreads();
    {
      s16x8 xv;
      xv[0] = f2bf(xf0.x); xv[1] = f2bf(xf0.y); xv[2] = f2bf(xf0.z); xv[3] = f2bf(xf0.w);
      xv[4] = f2bf(xf1.x); xv[5] = f2bf(xf1.y); xv[6] = f2bf(xf1.z); xv[7] = f2bf(xf1.w);
      *(s16x8*)&xa[sr * 72 + sc8] = xv;
    }
#pragma unroll
    for (int j = 0; j < 3; ++j) {
      *(s16x8*)&wb[(wr + 64 * j) * 72 + wo] = wreg[2 * j];
      *(s16x8*)&wb[(wr + 64 * j) * 72 + wo + 8] = wreg[2 * j + 1];
    }
    __syncthreads();

    if (it < 31) {
      const int k0n = (it + 1) * 64;
      xf0 = *(const float4*)(xp + k0n);
      xf1 = *(const float4*)(xp + k0n + 4);
#pragma unroll
      for (int j = 0; j < 3; ++j) {
        wreg[2 * j]     = *(const s16x8*)(wp + (size_t)(64 * j) * E_ + k0n);
        wreg[2 * j + 1] = *(const s16x8*)(wp + (size_t)(64 * j) * E_ + k0n + 8);
      }
    }

#pragma unroll
    for (int kc = 0; kc < 2; ++kc) {
      const int ko = kc * 32 + quad * 8;
      s16x8 af[2], bfr[3];
#pragma unroll
      for (int mg = 0; mg < 2; ++mg)
        af[mg] = *(const s16x8*)&xa[(mg * 16 + l15) * 72 + ko];
#pragma unroll
      for (int nt = 0; nt < 3; ++nt)
        bfr[nt] = *(const s16x8*)&wb[(wave * 48 + nt * 16 + l15) * 72 + ko];
#pragma unroll
      for (int mg = 0; mg < 2; ++mg)
#pragma unroll
        for (int nt = 0; nt < 3; ++nt)
          acc[mg][nt] = __builtin_amdgcn_mfma_f32_16x16x32_bf16(
              af[mg], bfr[nt], acc[mg][nt], 0, 0, 0);
    }
  }

  const float scale = 0.08838834764831845f;  // 1/sqrt(128), folded into Q
  const int b = row0 >> 12;
  const int s_base = row0 & (S_ - 1);
#pragma unroll
  for (int nt = 0; nt < 3; ++nt) {
    int col = nc0 + wave * 48 + nt * 16 + l15;
    int p = col >> 7;
    int h = col & (H_ - 1);
    if (p == 2) {
      float bsv = bv[h];
#pragma unroll
      for (int mg = 0; mg < 2; ++mg) {
        int s0 = s_base + mg * 16 + quad * 4;
        s16x4 vv;
#pragma unroll
        for (int r = 0; r < 4; ++r) vv[r] = f2bf(acc[mg][nt][r] + bsv);
        *(s16x4*)&Vt[((size_t)b * H_ + h) * S_ + s0] = vv;
      }
    } else if (p == 0) {
      float bsv = bq[h];
#pragma unroll
      for (int mg = 0; mg < 2; ++mg)
#pragma unroll
        for (int r = 0; r < 4; ++r) {
          int row = row0 + mg * 16 + quad * 4 + r;
          Q[(size_t)row * H_ + h] = f2bf((acc[mg][nt][r] + bsv) * scale);
        }
    } else {
      float bsv = bk[h];
#pragma unroll
      for (int mg = 0; mg < 2; ++mg)
#pragma unroll
        for (int r = 0; r < 4; ++r) {
          int row = row0 + mg * 16 + quad * 4 + r;
          K[(size_t)row * H_ + h] = f2bf(acc[mg][nt][r] + bsv);
        }
    }
  }
}

// ---------------------------------------------------------------------------
// Kernel 3: causal flash attention — R10 RESTRUCTURE.
// Diagnosis: R0/R7/R9 all pinned at ~137us, MfmaUtil 5%, all pipes >=75%
// idle at any occupancy. Per-CU issue work accounts for <25% of wall. The
// invariant: every K/V MFMA operand was a per-lane 16B load at 256B row
// stride = 16 discrete cache lines per 64-lane instruction, ~32/iter,
// effectively latency-serialized (32 x ~600cy x 8.5 iters ~= the wall).
// R9's qkv W-load regression (+28us from the same pattern) corroborates.
// New structure (the HK/AITER/CK form):
//  - 256 thr / 4 waves per block; q-tile 64; wave w owns rows 16w..16w+15
//    with INDEPENDENT online softmax -> cross-wave merge deleted.
//  - Per k-iter: stage K(64x128)+V(128x64) (32KB) into LDS with
//    global_load_lds width=16 (8 wave-instructions, each 1KB CONTIGUOUS),
//    double-buffered, one barrier/iter; loads for tile i+1 fly during
//    compute of tile i (drained by the barrier's vmcnt(0)).
//  - XOR swizzle ((row&7)<<4) applied on the GLOBAL source (LDS written
//    linearly, m173 pattern) and on the LDS read side; kills the 16-way
//    row-stride bank conflict, leaves ~2-way (free).
//  - Grid 256 = 1 block/CU; heavy tiles first; b = bid&3 keeps each batch
//    on its XCD group.
// ---------------------------------------------------------------------------
__global__ __launch_bounds__(256) void flash_attn(
    const short* __restrict__ Qb, const short* __restrict__ Kb,
    const short* __restrict__ Vtb, float* __restrict__ out) {
  __shared__ __attribute__((aligned(16))) short KT[2][64 * 128];   // 2x16KB
  __shared__ __attribute__((aligned(16))) short VT[2][128 * 64];   // 2x16KB
  __shared__ __attribute__((aligned(16))) short p_all[4 * 16 * 72];  // 9216B

  const int tid = threadIdx.x;
  const int w = tid >> 6;
  const int lane = tid & 63;
  const int l15 = lane & 15;
  const int quad = lane >> 4;
  const int bid = (int)blockIdx.x;
  const int b = bid & 3;           // batch stays XCD-grouped (bid%8 dispatch)
  const int T = 63 - (bid >> 2);   // heavy q-tiles first
  const int q0 = T * 64;
  const int nk = T + 1;            // 64-key tiles covering causal range
  const size_t bo = (size_t)b * S_ * H_;
  const short* Kg = Kb + bo;                       // [s][h], 256B rows
  const short* Vg = Vtb + (size_t)b * H_ * S_;     // [h][s], 8192B rows
  const float L2E = 1.4426950408889634f;
  short* p_lds = &p_all[w * (16 * 72)];

  // ---- per-lane staging address constants ----
  const int l_hi = lane >> 4;  // 0..3
  const int l_lo = lane & 15;  // 0..15
  int krow[4], kcol[4];
#pragma unroll
  for (int j = 0; j < 4; ++j) {
    int r = 16 * w + 4 * j + l_hi;                 // row in 64-row K tile
    krow[j] = r;
    kcol[j] = (l_lo << 4) ^ ((r & 7) << 4);        // pre-swizzled source col
  }
  const int vh_base = 32 * w + (lane >> 3);        // h row, +8j
  const int vcol = ((lane & 7) << 4) ^ (((lane >> 3) & 7) << 4);

  auto STAGE = [&](int sel, int kb) {
    const char* kgp = (const char*)Kg + (size_t)kb * 256;
    const char* vgp = (const char*)Vg + (size_t)kb * 2;
    char* kl = (char*)&KT[sel][0] + (16 * w) * 256;
    char* vl = (char*)&VT[sel][0] + (32 * w) * 128;
#pragma unroll
    for (int j = 0; j < 4; ++j) {
      gload_lds16(kgp + (size_t)krow[j] * 256 + kcol[j], kl + j * 1024);
      gload_lds16(vgp + (size_t)(vh_base + 8 * j) * 8192 + vcol, vl + j * 1024);
    }
  };

  // ---- Q fragments (per-wave rows), regs for whole tile ----
  s16x8 aq[4];
#pragma unroll
  for (int kt = 0; kt < 4; ++kt)
    aq[kt] = *(const s16x8*)(Qb + bo + (size_t)(q0 + 16 * w + l15) * H_ +
                             kt * 32 + quad * 8);

  f32x4 oacc[8];
#pragma unroll
  for (int nt = 0; nt < 8; ++nt) oacc[nt] = (f32x4){0.f, 0.f, 0.f, 0.f};
  float m_r[4], l_r[4];
#pragma unroll
  for (int r = 0; r < 4; ++r) { m_r[r] = -3.0e38f; l_r[r] = 0.f; }

  const int swr = (l15 & 7) << 4;  // read-side swizzle (row&7 == l15&7)

  int cur = 0;
  STAGE(0, 0);
  for (int i = 0; i < nk; ++i) {
    __syncthreads();  // buf[cur] staged (barrier drains vmcnt) + WAR guard
    if (i + 1 < nk) STAGE(cur ^ 1, (i + 1) * 64);

    const char* Kl = (const char*)&KT[cur][0];
    const char* Vl = (const char*)&VT[cur][0];

    // scores S = Q @ K^T (16 x 64), Q pre-scaled; K frags from swizzled LDS
    f32x4 sc[4];
#pragma unroll
    for (int nt = 0; nt < 4; ++nt) {
      f32x4 a = (f32x4){0.f, 0.f, 0.f, 0.f};
#pragma unroll
      for (int kt = 0; kt < 4; ++kt) {
        const s16x8 kf = *(const s16x8*)(Kl + (nt * 16 + l15) * 256 +
                                         ((kt * 64 + quad * 16) ^ swr));
        a = __builtin_amdgcn_mfma_f32_16x16x32_bf16(aq[kt], kf, a, 0, 0, 0);
      }
      sc[nt] = a;
    }

    if (i == nk - 1) {  // diagonal k-tile: causal mask (rows 16w.. per wave)
      const int qloc = 16 * w + quad * 4;
#pragma unroll
      for (int nt = 0; nt < 4; ++nt)
#pragma unroll
        for (int r = 0; r < 4; ++r)
          if (nt * 16 + l15 > qloc + r) sc[nt][r] = -3.0e38f;
    }

    // online softmax: row max over 64 cols via DPP butterfly
    float al[4];
#pragma unroll
    for (int r = 0; r < 4; ++r) {
      float vm = rowmax16(
          fmaxf(fmaxf(sc[0][r], sc[1][r]), fmaxf(sc[2][r], sc[3][r])));
      float mn = fmaxf(m_r[r], vm);
      al[r] = exp2f((m_r[r] - mn) * L2E);
      m_r[r] = mn;
    }
#pragma unroll
    for (int r = 0; r < 4; ++r) {
      float s = 0.f;
#pragma unroll
      for (int nt = 0; nt < 4; ++nt) {
        float pv = exp2f((sc[nt][r] - m_r[r]) * L2E);
        sc[nt][r] = pv;
        s += pv;
      }
      l_r[r] = l_r[r] * al[r] + rowsum16(s);
    }

    // P (C-layout) -> per-wave LDS (bf16), then re-read as A-layout frags
    __asm__ volatile("s_waitcnt lgkmcnt(0)" ::: "memory");  // WAR vs prior reads
#pragma unroll
    for (int nt = 0; nt < 4; ++nt)
#pragma unroll
      for (int r = 0; r < 4; ++r)
        p_lds[(quad * 4 + r) * 72 + nt * 16 + l15] = f2bf(sc[nt][r]);

    // rescale O while the LDS writes land
#pragma unroll
    for (int nt = 0; nt < 8; ++nt)
#pragma unroll
      for (int r = 0; r < 4; ++r) oacc[nt][r] *= al[r];

    __asm__ volatile("s_waitcnt lgkmcnt(0)" ::: "memory");  // RAW: writes visible
    s16x8 ap[2];
#pragma unroll
    for (int kt2 = 0; kt2 < 2; ++kt2)
      ap[kt2] = *(const s16x8*)&p_lds[l15 * 72 + kt2 * 32 + quad * 8];

    // O += P @ V ; V frags from swizzled LDS [h][s]
#pragma unroll
    for (int nt = 0; nt < 8; ++nt) {
#pragma unroll
      for (int kt2 = 0; kt2 < 2; ++kt2) {
        const s16x8 vf = *(const s16x8*)(Vl + (nt * 16 + l15) * 128 +
                                         ((kt2 * 64 + quad * 16) ^ swr));
        oacc[nt] = __builtin_amdgcn_mfma_f32_16x16x32_bf16(
            ap[kt2], vf, oacc[nt], 0, 0, 0);
      }
    }

    cur ^= 1;
  }

  // ---- epilogue: per-wave rows, direct normalized store (no merge) ----
  float invl[4];
#pragma unroll
  for (int r = 0; r < 4; ++r) invl[r] = 1.0f / l_r[r];
#pragma unroll
  for (int nt = 0; nt < 8; ++nt)
#pragma unroll
    for (int r = 0; r < 4; ++r)
      out[bo + (size_t)(q0 + 16 * w + quad * 4 + r) * H_ + nt * 16 + l15] =
          oacc[nt][r] * invl[r];
}

// ---------------------------------------------------------------------------
extern "C" void kernel_launch(void* const* d_in, const int* in_sizes, int n_in,
                              void* d_out, int out_size, void* d_ws, size_t ws_size,
                              hipStream_t stream) {
  const float* x  = (const float*)d_in[0];
  const float* Wq = (const float*)d_in[1];
  const float* bq = (const float*)d_in[2];
  const float* Wk = (const float*)d_in[3];
  const float* bk = (const float*)d_in[4];
  const float* Wv = (const float*)d_in[5];
  const float* bv = (const float*)d_in[6];

  // ws layout: Wt (384*2048 bf16) | Q | K | Vt (each B*S*H bf16) ~= 13.5 MB
  short* Wt = (short*)d_ws;
  short* Q  = Wt + (size_t)384 * E_;
  short* K  = Q + (size_t)B_ * S_ * H_;
  short* Vt = K + (size_t)B_ * S_ * H_;
  float* out = (float*)d_out;

  hipLaunchKernelGGL(prep_weights, dim3(64 * 4, 3), dim3(256), 0, stream,
                     Wq, Wk, Wv, Wt);
  hipLaunchKernelGGL(qkv_gemm, dim3((B_ * S_) / 32 * 2), dim3(256), 0, stream,
                     x, Wt, bq, bk, bv, Q, K, Vt);
  // 256 blocks (1/CU): 64 q-tiles of 64 rows x 4 batches, heavy-first
  hipLaunchKernelGGL(flash_attn, dim3(64 * B_), dim3(256), 0, stream,
                     Q, K, Vt, out);
}

// Round 6
// 373.658 us; speedup vs baseline: 1.1493x; 1.0117x over previous
//
#include <hip/hip_runtime.h>

#define B_ 4
#define S_ 4096
#define E_ 2048
#define H_ 128

using f32x4 = __attribute__((ext_vector_type(4))) float;
using s16x8 = __attribute__((ext_vector_type(8))) short;
using s16x4 = __attribute__((ext_vector_type(4))) short;

// fp32 -> bf16 bits, round-to-nearest-even
__device__ __forceinline__ short f2bf(float f) {
  unsigned u = __float_as_uint(f);
  u += 0x7FFFu + ((u >> 16) & 1u);
  return (short)(u >> 16);
}

// async global(16B/lane, per-lane addr) -> LDS (wave-uniform base + lane*16)
__device__ __forceinline__ void gload_lds16(const void* g, void* l) {
  __builtin_amdgcn_global_load_lds(
      (const __attribute__((address_space(1))) void*)g,
      (__attribute__((address_space(3))) void*)l, 16, 0, 0);
}

// K=16 bf16 MFMA: D(16q x 16h) = A(16q x 16k) * B(16k x 16h) + C
// Prefer the gfx90a-era _1k builtin (signature = short4, stable), then the
// gfx950 spelling, then raw asm (instruction exists on gfx950 per ISA §10).
__device__ __forceinline__ f32x4 mfma16x16x16(s16x4 a, s16x4 b, f32x4 c) {
#if __has_builtin(__builtin_amdgcn_mfma_f32_16x16x16bf16_1k)
  return __builtin_amdgcn_mfma_f32_16x16x16bf16_1k(a, b, c, 0, 0, 0);
#elif __has_builtin(__builtin_amdgcn_mfma_f32_16x16x16_bf16)
  return __builtin_amdgcn_mfma_f32_16x16x16_bf16(a, b, c, 0, 0, 0);
#else
  f32x4 d;
  asm("v_mfma_f32_16x16x16_bf16 %0, %1, %2, %3"
      : "=v"(d) : "v"(a), "v"(b), "v"(c));
  return d;
#endif
}

// ---------------------------------------------------------------------------
// Kernel 1: W (E x H fp32) x3 -> Wt (384 x 2048 bf16) via LDS tile transpose.
// ---------------------------------------------------------------------------
__global__ __launch_bounds__(256) void prep_weights(
    const float* __restrict__ Wq, const float* __restrict__ Wk,
    const float* __restrict__ Wv, short* __restrict__ Wt) {
  __shared__ float T[32 * 33];
  int p = blockIdx.y;
  const float* W = (p == 0) ? Wq : ((p == 1) ? Wk : Wv);
  int e0 = (blockIdx.x & 63) * 32;
  int h0 = (blockIdx.x >> 6) * 32;
  int r = threadIdx.x >> 5;
  int c = threadIdx.x & 31;
#pragma unroll
  for (int i = 0; i < 4; ++i) {
    int e = r + 8 * i;
    T[c * 33 + e] = W[(size_t)(e0 + e) * H_ + h0 + c];
  }
  __syncthreads();
#pragma unroll
  for (int i = 0; i < 4; ++i) {
    int h = r + 8 * i;
    Wt[(size_t)(p * H_ + h0 + h) * E_ + e0 + c] = f2bf(T[h * 33 + c]);
  }
}

// ---------------------------------------------------------------------------
// Kernel 2: fused QKV projection GEMM, BK=64 (R0 version, unchanged).
// ---------------------------------------------------------------------------
__global__ __launch_bounds__(256) void qkv_gemm(
    const float* __restrict__ x, const short* __restrict__ Wt,
    const float* __restrict__ bq, const float* __restrict__ bk,
    const float* __restrict__ bv,
    short* __restrict__ Q, short* __restrict__ K, short* __restrict__ Vt) {
  __shared__ __attribute__((aligned(16))) short xa[32 * 72];
  __shared__ __attribute__((aligned(16))) short wb[192 * 72];

  const int tid = threadIdx.x;
  const int wave = tid >> 6;
  const int lane = tid & 63;
  const int l15 = lane & 15;
  const int quad = lane >> 4;
  const int row0 = (blockIdx.x >> 1) * 32;
  const int nc0 = (blockIdx.x & 1) * 192;

  f32x4 acc[2][3];
#pragma unroll
  for (int mg = 0; mg < 2; ++mg)
#pragma unroll
    for (int nt = 0; nt < 3; ++nt) acc[mg][nt] = (f32x4){0.f, 0.f, 0.f, 0.f};

  const int sr = tid >> 3;
  const int sc8 = (tid & 7) * 8;
  const int wr = tid >> 2;
  const int wo = (tid & 3) * 16;
  const float* xp = x + (size_t)(row0 + sr) * E_ + sc8;
  const short* wp = Wt + (size_t)(nc0 + wr) * E_ + wo;

  float4 xf0 = *(const float4*)(xp);
  float4 xf1 = *(const float4*)(xp + 4);
  s16x8 wreg[6];
#pragma unroll
  for (int j = 0; j < 3; ++j) {
    wreg[2 * j]     = *(const s16x8*)(wp + (size_t)(64 * j) * E_);
    wreg[2 * j + 1] = *(const s16x8*)(wp + (size_t)(64 * j) * E_ + 8);
  }

  for (int it = 0; it < 32; ++it) {
    __syncthreads();
    {
      s16x8 xv;
      xv[0] = f2bf(xf0.x); xv[1] = f2bf(xf0.y); xv[2] = f2bf(xf0.z); xv[3] = f2bf(xf0.w);
      xv[4] = f2bf(xf1.x); xv[5] = f2bf(xf1.y); xv[6] = f2bf(xf1.z); xv[7] = f2bf(xf1.w);
      *(s16x8*)&xa[sr * 72 + sc8] = xv;
    }
#pragma unroll
    for (int j = 0; j < 3; ++j) {
      *(s16x8*)&wb[(wr + 64 * j) * 72 + wo] = wreg[2 * j];
      *(s16x8*)&wb[(wr + 64 * j) * 72 + wo + 8] = wreg[2 * j + 1];
    }
    __syncthreads();

    if (it < 31) {
      const int k0n = (it + 1) * 64;
      xf0 = *(const float4*)(xp + k0n);
      xf1 = *(const float4*)(xp + k0n + 4);
#pragma unroll
      for (int j = 0; j < 3; ++j) {
        wreg[2 * j]     = *(const s16x8*)(wp + (size_t)(64 * j) * E_ + k0n);
        wreg[2 * j + 1] = *(const s16x8*)(wp + (size_t)(64 * j) * E_ + k0n + 8);
      }
    }

#pragma unroll
    for (int kc = 0; kc < 2; ++kc) {
      const int ko = kc * 32 + quad * 8;
      s16x8 af[2], bfr[3];
#pragma unroll
      for (int mg = 0; mg < 2; ++mg)
        af[mg] = *(const s16x8*)&xa[(mg * 16 + l15) * 72 + ko];
#pragma unroll
      for (int nt = 0; nt < 3; ++nt)
        bfr[nt] = *(const s16x8*)&wb[(wave * 48 + nt * 16 + l15) * 72 + ko];
#pragma unroll
      for (int mg = 0; mg < 2; ++mg)
#pragma unroll
        for (int nt = 0; nt < 3; ++nt)
          acc[mg][nt] = __builtin_amdgcn_mfma_f32_16x16x32_bf16(
              af[mg], bfr[nt], acc[mg][nt], 0, 0, 0);
    }
  }

  const float scale = 0.08838834764831845f;  // 1/sqrt(128), folded into Q
  const int b = row0 >> 12;
  const int s_base = row0 & (S_ - 1);
#pragma unroll
  for (int nt = 0; nt < 3; ++nt) {
    int col = nc0 + wave * 48 + nt * 16 + l15;
    int p = col >> 7;
    int h = col & (H_ - 1);
    if (p == 2) {
      float bsv = bv[h];
#pragma unroll
      for (int mg = 0; mg < 2; ++mg) {
        int s0 = s_base + mg * 16 + quad * 4;
        s16x4 vv;
#pragma unroll
        for (int r = 0; r < 4; ++r) vv[r] = f2bf(acc[mg][nt][r] + bsv);
        *(s16x4*)&Vt[((size_t)b * H_ + h) * S_ + s0] = vv;
      }
    } else if (p == 0) {
      float bsv = bq[h];
#pragma unroll
      for (int mg = 0; mg < 2; ++mg)
#pragma unroll
        for (int r = 0; r < 4; ++r) {
          int row = row0 + mg * 16 + quad * 4 + r;
          Q[(size_t)row * H_ + h] = f2bf((acc[mg][nt][r] + bsv) * scale);
        }
    } else {
      float bsv = bk[h];
#pragma unroll
      for (int mg = 0; mg < 2; ++mg)
#pragma unroll
        for (int r = 0; r < 4; ++r) {
          int row = row0 + mg * 16 + quad * 4 + r;
          K[(size_t)row * H_ + h] = f2bf(acc[mg][nt][r] + bsv);
        }
    }
  }
}

// ---------------------------------------------------------------------------
// Kernel 3: causal flash attention — R12 (= R11 theory + audit fixes).
//  (1) SWAPPED QK^T: mfma(K_frag, Q_frag) -> D = S^T (lane = q-col, 4 keys
//      per lane) = A-frag layout of K=16 PV MFMA. P stays in registers;
//      the p_lds bounce and both lgkmcnt(0) drains are deleted.
//  (2) PV via v_mfma_f32_16x16x16_bf16 (2 per ht), V as b64 frags from
//      the swizzled LDS tile.
//  (3) 2-way KEY-SPLIT, 8 waves (512 thr): wave (rg,kh) owns rows 16*rg,
//      keys kh*32.. of each 64-key tile. Partner m-merge = asm s_barrier
//      with "memory" clobber (compiler fence; staging vmcnt stays in
//      flight). O halves merged once at end through the dead KT buffer.
// Audit fixes vs R11: __syncthreads() BEFORE the KT-as-Ob reuse (race);
// s_barrier as asm+memory (no LDS-read hoisting); _1k builtin preferred.
// Staging/double-buffer/swizzle identical to R10 (verified correct).
// ---------------------------------------------------------------------------
__global__ __launch_bounds__(512) void flash_attn(
    const short* __restrict__ Qb, const short* __restrict__ Kb,
    const short* __restrict__ Vtb, float* __restrict__ out) {
  __shared__ __attribute__((aligned(16))) short KT[2][64 * 128];  // 2x16KB
  __shared__ __attribute__((aligned(16))) short VT[2][128 * 64];  // 2x16KB
  __shared__ float mx[2][8][16];                                  // 1KB
  __shared__ float lx[8][16];                                     // 512B

  const int tid = threadIdx.x;
  const int w = tid >> 6;
  const int lane = tid & 63;
  const int l15 = lane & 15;
  const int quad = lane >> 4;
  const int rg = w & 3;        // row-group: rows 16*rg .. 16*rg+15
  const int kh = w >> 2;       // key-half: keys kh*32 .. kh*32+31
  const int bid = (int)blockIdx.x;
  const int b = bid & 3;
  const int T = 63 - (bid >> 2);   // heavy q-tiles first
  const int q0 = T * 64;
  const int nk = T + 1;
  const size_t bo = (size_t)b * S_ * H_;
  const short* Kg = Kb + bo;                    // [s][h], 256B rows
  const short* Vg = Vtb + (size_t)b * H_ * S_;  // [h][s], 8192B rows
  const float L2E = 1.4426950408889634f;

  // ---- staging: wave w covers K rows 8w..8w+7, V rows 16w..16w+15 ----
  auto STAGE = [&](int sel, int kb) {
    const char* kgp = (const char*)Kg + (size_t)kb * 256;
    const char* vgp = (const char*)Vg + (size_t)kb * 2;
    char* kl = (char*)&KT[sel][0] + (8 * w) * 256;
    char* vl = (char*)&VT[sel][0] + (16 * w) * 128;
#pragma unroll
    for (int j = 0; j < 2; ++j) {
      int krow = 8 * w + 4 * j + (lane >> 4);
      int kcol = ((lane & 15) << 4) ^ ((((lane >> 4) + 4 * j) & 7) << 4);
      gload_lds16(kgp + (size_t)krow * 256 + kcol, kl + j * 1024);
      int vrow = 16 * w + 8 * j + (lane >> 3);
      int vcol = ((lane & 7) << 4) ^ (((lane >> 3) & 7) << 4);
      gload_lds16(vgp + (size_t)vrow * 8192 + vcol, vl + j * 1024);
    }
  };

  // ---- Q fragments: B-frag of swapped QK^T (same bytes as A-frag) ----
  s16x8 aq[4];
#pragma unroll
  for (int kt = 0; kt < 4; ++kt)
    aq[kt] = *(const s16x8*)(Qb + bo + (size_t)(q0 + 16 * rg + l15) * H_ +
                             kt * 32 + quad * 8);

  f32x4 oacc[8];
#pragma unroll
  for (int nt = 0; nt < 8; ++nt) oacc[nt] = (f32x4){0.f, 0.f, 0.f, 0.f};
  float m15 = -3.0e38f;              // running max for q = l15
  float mT[4];                       // running max for q = quad*4+r
  float l15acc = 0.f;                // partial l (this lane's keys), q = l15
#pragma unroll
  for (int r = 0; r < 4; ++r) mT[r] = -3.0e38f;

  const int swr = (l15 & 7) << 4;    // read-side swizzle
  const int q4 = quad * 4;

  int cur = 0;
  STAGE(0, 0);
  for (int i = 0; i < nk; ++i) {
    __syncthreads();  // buf[cur] staged (drains vmcnt) + WAR guard
    if (i + 1 < nk) STAGE(cur ^ 1, (i + 1) * 64);

    const char* Kl = (const char*)&KT[cur][0];
    const char* Vl = (const char*)&VT[cur][0];

    // S^T tiles: sc[nt] rows = keys kh*32+nt*16+quad*4+r, col = q = l15
    f32x4 sc[2];
#pragma unroll
    for (int nt = 0; nt < 2; ++nt) {
      f32x4 a = (f32x4){0.f, 0.f, 0.f, 0.f};
      const int krow = kh * 32 + nt * 16 + l15;
#pragma unroll
      for (int kt = 0; kt < 4; ++kt) {
        const s16x8 kf = *(const s16x8*)(Kl + krow * 256 +
                                         ((kt * 64 + quad * 16) ^ swr));
        a = __builtin_amdgcn_mfma_f32_16x16x32_bf16(kf, aq[kt], a, 0, 0, 0);
      }
      sc[nt] = a;
    }

    if (i == nk - 1) {  // diagonal tile: causal mask, key_local > q_local
      const int qrow = 16 * rg + l15;
#pragma unroll
      for (int nt = 0; nt < 2; ++nt)
#pragma unroll
        for (int r = 0; r < 4; ++r)
          if (kh * 32 + nt * 16 + q4 + r > qrow) sc[nt][r] = -3.0e38f;
    }

    // per-lane max over this wave's 8 keys, then cross-quad (xor 16/32)
    float vm = fmaxf(fmaxf(fmaxf(sc[0][0], sc[0][1]), fmaxf(sc[0][2], sc[0][3])),
                     fmaxf(fmaxf(sc[1][0], sc[1][1]), fmaxf(sc[1][2], sc[1][3])));
    vm = fmaxf(vm, __shfl_xor(vm, 16));
    vm = fmaxf(vm, __shfl_xor(vm, 32));
    const int par = i & 1;
    if (lane < 16) mx[par][w][lane] = vm;
    __asm__ volatile("s_waitcnt lgkmcnt(0)" ::: "memory");
    // raw barrier (staging vmcnt stays in flight); "memory" clobber stops
    // the compiler from hoisting the partner-mx read above it
    __asm__ volatile("s_barrier" ::: "memory");

    // merged tile max for q=l15 (P path) and q=quad*4+r (rescale path)
    float tile_m = fmaxf(vm, mx[par][w ^ 4][l15]);
    float mn = fmaxf(m15, tile_m);
    float al15 = exp2f((m15 - mn) * L2E);
    m15 = mn;
    float alT[4];
#pragma unroll
    for (int r = 0; r < 4; ++r) {
      float a2 = fmaxf(mx[par][w][q4 + r], mx[par][w ^ 4][q4 + r]);
      float mnT = fmaxf(mT[r], a2);
      alT[r] = exp2f((mT[r] - mnT) * L2E);
      mT[r] = mnT;
    }

    // P in-register -> PV A-frags (K=16): ap[nt][r] = P[q=l15][key q4+r]
    s16x4 ap[2];
    float lpart = 0.f;
#pragma unroll
    for (int nt = 0; nt < 2; ++nt)
#pragma unroll
      for (int r = 0; r < 4; ++r) {
        float pv = exp2f((sc[nt][r] - m15) * L2E);
        lpart += pv;
        ap[nt][r] = f2bf(pv);
      }
    l15acc = l15acc * al15 + lpart;

    // rescale O (rows q = quad*4+r)
#pragma unroll
    for (int ht = 0; ht < 8; ++ht)
#pragma unroll
      for (int r = 0; r < 4; ++r) oacc[ht][r] *= alT[r];

    // O += P @ V : B-frag = V[key=q4+j][h=ht*16+l15] from swizzled LDS
#pragma unroll
    for (int ht = 0; ht < 8; ++ht) {
#pragma unroll
      for (int nt = 0; nt < 2; ++nt) {
        const s16x4 vf = *(const s16x4*)(Vl + (ht * 16 + l15) * 128 +
                                         ((kh * 64 + nt * 32 + quad * 8) ^ swr));
        oacc[ht] = mfma16x16x16(ap[nt], vf, oacc[ht]);
      }
    }

    cur ^= 1;
  }

  // ---- epilogue: l reduce (quad + partner), O merge across key-halves ----
  float lw = l15acc;
  lw += __shfl_xor(lw, 16);
  lw += __shfl_xor(lw, 32);
  if (lane < 16) lx[w][lane] = lw;
  __syncthreads();  // ALL waves done reading KT/VT; lx visible (race fix)

  float* Ob = (float*)&KT[0][0];  // 32KB: [rg][16 rows][128 cols], KT dead
  if (kh == 1) {
#pragma unroll
    for (int ht = 0; ht < 8; ++ht)
#pragma unroll
      for (int r = 0; r < 4; ++r)
        Ob[rg * 2048 + (q4 + r) * 128 + ht * 16 + l15] = oacc[ht][r];
  }
  __syncthreads();
  if (kh == 0) {
    float invl[4];
#pragma unroll
    for (int r = 0; r < 4; ++r)
      invl[r] = 1.0f / (lx[w][q4 + r] + lx[w ^ 4][q4 + r]);
#pragma unroll
    for (int ht = 0; ht < 8; ++ht)
#pragma unroll
      for (int r = 0; r < 4; ++r) {
        float o = oacc[ht][r] + Ob[rg * 2048 + (q4 + r) * 128 + ht * 16 + l15];
        out[bo + (size_t)(q0 + 16 * rg + q4 + r) * H_ + ht * 16 + l15] =
            o * invl[r];
      }
  }
}

// ---------------------------------------------------------------------------
extern "C" void kernel_launch(void* const* d_in, const int* in_sizes, int n_in,
                              void* d_out, int out_size, void* d_ws, size_t ws_size,
                              hipStream_t stream) {
  const float* x  = (const float*)d_in[0];
  const float* Wq = (const float*)d_in[1];
  const float* bq = (const float*)d_in[2];
  const float* Wk = (const float*)d_in[3];
  const float* bk = (const float*)d_in[4];
  const float* Wv = (const float*)d_in[5];
  const float* bv = (const float*)d_in[6];

  // ws layout: Wt (384*2048 bf16) | Q | K | Vt (each B*S*H bf16) ~= 13.5 MB
  short* Wt = (short*)d_ws;
  short* Q  = Wt + (size_t)384 * E_;
  short* K  = Q + (size_t)B_ * S_ * H_;
  short* Vt = K + (size_t)B_ * S_ * H_;
  float* out = (float*)d_out;

  hipLaunchKernelGGL(prep_weights, dim3(64 * 4, 3), dim3(256), 0, stream,
                     Wq, Wk, Wv, Wt);
  hipLaunchKernelGGL(qkv_gemm, dim3((B_ * S_) / 32 * 2), dim3(256), 0, stream,
                     x, Wt, bq, bk, bv, Q, K, Vt);
  // 256 blocks, 512 thr (8 waves): 64 q-tiles x 4 batches, heavy-first
  hipLaunchKernelGGL(flash_attn, dim3(64 * B_), dim3(512), 0, stream,
                     Q, K, Vt, out);
}

// Round 7
// 322.718 us; speedup vs baseline: 1.3307x; 1.1578x over previous
//
#include <hip/hip_runtime.h>

#define B_ 4
#define S_ 4096
#define E_ 2048
#define H_ 128

using f32x4 = __attribute__((ext_vector_type(4))) float;
using s16x8 = __attribute__((ext_vector_type(8))) short;
using s16x4 = __attribute__((ext_vector_type(4))) short;

// fp32 -> bf16 bits, round-to-nearest-even
__device__ __forceinline__ short f2bf(float f) {
  unsigned u = __float_as_uint(f);
  u += 0x7FFFu + ((u >> 16) & 1u);
  return (short)(u >> 16);
}

// async global(16B/lane, per-lane addr) -> LDS (wave-uniform base + lane*16)
__device__ __forceinline__ void gload_lds16(const void* g, void* l) {
  __builtin_amdgcn_global_load_lds(
      (const __attribute__((address_space(1))) void*)g,
      (__attribute__((address_space(3))) void*)l, 16, 0, 0);
}

// K=16 bf16 MFMA: D(16q x 16h) = A(16q x 16k) * B(16k x 16h) + C
__device__ __forceinline__ f32x4 mfma16x16x16(s16x4 a, s16x4 b, f32x4 c) {
#if __has_builtin(__builtin_amdgcn_mfma_f32_16x16x16bf16_1k)
  return __builtin_amdgcn_mfma_f32_16x16x16bf16_1k(a, b, c, 0, 0, 0);
#elif __has_builtin(__builtin_amdgcn_mfma_f32_16x16x16_bf16)
  return __builtin_amdgcn_mfma_f32_16x16x16_bf16(a, b, c, 0, 0, 0);
#else
  f32x4 d;
  asm("v_mfma_f32_16x16x16_bf16 %0, %1, %2, %3"
      : "=v"(d) : "v"(a), "v"(b), "v"(c));
  return d;
#endif
}

// ---------------------------------------------------------------------------
// Kernel 1: W (E x H fp32) x3 -> Wt (384 x 2048 bf16) via LDS tile transpose.
// ---------------------------------------------------------------------------
__global__ __launch_bounds__(256) void prep_weights(
    const float* __restrict__ Wq, const float* __restrict__ Wk,
    const float* __restrict__ Wv, short* __restrict__ Wt) {
  __shared__ float T[32 * 33];
  int p = blockIdx.y;
  const float* W = (p == 0) ? Wq : ((p == 1) ? Wk : Wv);
  int e0 = (blockIdx.x & 63) * 32;
  int h0 = (blockIdx.x >> 6) * 32;
  int r = threadIdx.x >> 5;
  int c = threadIdx.x & 31;
#pragma unroll
  for (int i = 0; i < 4; ++i) {
    int e = r + 8 * i;
    T[c * 33 + e] = W[(size_t)(e0 + e) * H_ + h0 + c];
  }
  __syncthreads();
#pragma unroll
  for (int i = 0; i < 4; ++i) {
    int h = r + 8 * i;
    Wt[(size_t)(p * H_ + h0 + h) * E_ + e0 + c] = f2bf(T[h * 33 + c]);
  }
}

// ---------------------------------------------------------------------------
// Kernel 2: fused QKV projection GEMM, BK=64 (R0 version, unchanged).
// ---------------------------------------------------------------------------
__global__ __launch_bounds__(256) void qkv_gemm(
    const float* __restrict__ x, const short* __restrict__ Wt,
    const float* __restrict__ bq, const float* __restrict__ bk,
    const float* __restrict__ bv,
    short* __restrict__ Q, short* __restrict__ K, short* __restrict__ Vt) {
  __shared__ __attribute__((aligned(16))) short xa[32 * 72];
  __shared__ __attribute__((aligned(16))) short wb[192 * 72];

  const int tid = threadIdx.x;
  const int wave = tid >> 6;
  const int lane = tid & 63;
  const int l15 = lane & 15;
  const int quad = lane >> 4;
  const int row0 = (blockIdx.x >> 1) * 32;
  const int nc0 = (blockIdx.x & 1) * 192;

  f32x4 acc[2][3];
#pragma unroll
  for (int mg = 0; mg < 2; ++mg)
#pragma unroll
    for (int nt = 0; nt < 3; ++nt) acc[mg][nt] = (f32x4){0.f, 0.f, 0.f, 0.f};

  const int sr = tid >> 3;
  const int sc8 = (tid & 7) * 8;
  const int wr = tid >> 2;
  const int wo = (tid & 3) * 16;
  const float* xp = x + (size_t)(row0 + sr) * E_ + sc8;
  const short* wp = Wt + (size_t)(nc0 + wr) * E_ + wo;

  float4 xf0 = *(const float4*)(xp);
  float4 xf1 = *(const float4*)(xp + 4);
  s16x8 wreg[6];
#pragma unroll
  for (int j = 0; j < 3; ++j) {
    wreg[2 * j]     = *(const s16x8*)(wp + (size_t)(64 * j) * E_);
    wreg[2 * j + 1] = *(const s16x8*)(wp + (size_t)(64 * j) * E_ + 8);
  }

  for (int it = 0; it < 32; ++it) {
    __syncthreads();
    {
      s16x8 xv;
      xv[0] = f2bf(xf0.x); xv[1] = f2bf(xf0.y); xv[2] = f2bf(xf0.z); xv[3] = f2bf(xf0.w);
      xv[4] = f2bf(xf1.x); xv[5] = f2bf(xf1.y); xv[6] = f2bf(xf1.z); xv[7] = f2bf(xf1.w);
      *(s16x8*)&xa[sr * 72 + sc8] = xv;
    }
#pragma unroll
    for (int j = 0; j < 3; ++j) {
      *(s16x8*)&wb[(wr + 64 * j) * 72 + wo] = wreg[2 * j];
      *(s16x8*)&wb[(wr + 64 * j) * 72 + wo + 8] = wreg[2 * j + 1];
    }
    __syncthreads();

    if (it < 31) {
      const int k0n = (it + 1) * 64;
      xf0 = *(const float4*)(xp + k0n);
      xf1 = *(const float4*)(xp + k0n + 4);
#pragma unroll
      for (int j = 0; j < 3; ++j) {
        wreg[2 * j]     = *(const s16x8*)(wp + (size_t)(64 * j) * E_ + k0n);
        wreg[2 * j + 1] = *(const s16x8*)(wp + (size_t)(64 * j) * E_ + k0n + 8);
      }
    }

#pragma unroll
    for (int kc = 0; kc < 2; ++kc) {
      const int ko = kc * 32 + quad * 8;
      s16x8 af[2], bfr[3];
#pragma unroll
      for (int mg = 0; mg < 2; ++mg)
        af[mg] = *(const s16x8*)&xa[(mg * 16 + l15) * 72 + ko];
#pragma unroll
      for (int nt = 0; nt < 3; ++nt)
        bfr[nt] = *(const s16x8*)&wb[(wave * 48 + nt * 16 + l15) * 72 + ko];
#pragma unroll
      for (int mg = 0; mg < 2; ++mg)
#pragma unroll
        for (int nt = 0; nt < 3; ++nt)
          acc[mg][nt] = __builtin_amdgcn_mfma_f32_16x16x32_bf16(
              af[mg], bfr[nt], acc[mg][nt], 0, 0, 0);
    }
  }

  const float scale = 0.08838834764831845f;  // 1/sqrt(128), folded into Q
  const int b = row0 >> 12;
  const int s_base = row0 & (S_ - 1);
#pragma unroll
  for (int nt = 0; nt < 3; ++nt) {
    int col = nc0 + wave * 48 + nt * 16 + l15;
    int p = col >> 7;
    int h = col & (H_ - 1);
    if (p == 2) {
      float bsv = bv[h];
#pragma unroll
      for (int mg = 0; mg < 2; ++mg) {
        int s0 = s_base + mg * 16 + quad * 4;
        s16x4 vv;
#pragma unroll
        for (int r = 0; r < 4; ++r) vv[r] = f2bf(acc[mg][nt][r] + bsv);
        *(s16x4*)&Vt[((size_t)b * H_ + h) * S_ + s0] = vv;
      }
    } else if (p == 0) {
      float bsv = bq[h];
#pragma unroll
      for (int mg = 0; mg < 2; ++mg)
#pragma unroll
        for (int r = 0; r < 4; ++r) {
          int row = row0 + mg * 16 + quad * 4 + r;
          Q[(size_t)row * H_ + h] = f2bf((acc[mg][nt][r] + bsv) * scale);
        }
    } else {
      float bsv = bk[h];
#pragma unroll
      for (int mg = 0; mg < 2; ++mg)
#pragma unroll
        for (int r = 0; r < 4; ++r) {
          int row = row0 + mg * 16 + quad * 4 + r;
          K[(size_t)row * H_ + h] = f2bf(acc[mg][nt][r] + bsv);
        }
    }
  }
}

// ---------------------------------------------------------------------------
// Kernel 3: causal flash attention — R13 = R12 inner loop + SPLIT-K blocks.
// R12 post-mortem: wall still ~4800cy/iter; grid 256 = 1 block/CU means
// wall = MAX block (64 iters) vs mean 32.5 (guaranteed 2x loss), and no
// co-resident block to fill serial-chain bubbles (DS+VALU+MFMA pipe work
// is only ~2300+965+600cy of the 4800).
// Fix: each (batch, q-tile) is computed by TWO blocks: half 0 = key-tiles
// [0, ceil(nk/2)), half 1 = rest (diagonal stays in last global tile; mask
// code unchanged). Grid 512 -> 2 blocks/CU (LDS 2x67KB=134<=160). Heaviest
// block 32 iters; per-CU mean 32.5 -> wall ~= mean, bubbles cross-filled.
// Halves write UNNORMALIZED partial O + per-row (m,l): half0 -> out buffer,
// half1 -> ws; merge_halves combines. Staging volume unchanged (disjoint
// key ranges). Inner loop/staging/swizzle byte-identical to R12 (verified).
// ---------------------------------------------------------------------------
__global__ __launch_bounds__(512) void flash_attn(
    const short* __restrict__ Qb, const short* __restrict__ Kb,
    const short* __restrict__ Vtb, float* __restrict__ O0,
    float* __restrict__ O1, float* __restrict__ ML) {
  __shared__ __attribute__((aligned(16))) short KT[2][64 * 128];  // 2x16KB
  __shared__ __attribute__((aligned(16))) short VT[2][128 * 64];  // 2x16KB
  __shared__ float mx[2][8][16];                                  // 1KB
  __shared__ float lx[8][16];                                     // 512B

  const int tid = threadIdx.x;
  const int w = tid >> 6;
  const int lane = tid & 63;
  const int l15 = lane & 15;
  const int quad = lane >> 4;
  const int rg = w & 3;        // row-group: rows 16*rg .. 16*rg+15
  const int kh = w >> 2;       // key-half within tile: keys kh*32 ..
  const int bid = (int)blockIdx.x;
  const int half = bid & 1;    // split-K half
  const int slot = bid >> 1;
  const int b = slot & 3;
  const int T = 63 - (slot >> 2);  // heavy q-tiles first
  const int q0 = T * 64;
  const int nk = T + 1;
  const int hsplit = (nk + 1) >> 1;
  const int i0 = half ? hsplit : 0;
  const int i1 = half ? nk : hsplit;
  const size_t bo = (size_t)b * S_ * H_;
  const short* Kg = Kb + bo;                    // [s][h], 256B rows
  const short* Vg = Vtb + (size_t)b * H_ * S_;  // [h][s], 8192B rows
  const float L2E = 1.4426950408889634f;

  // ---- staging: wave w covers K rows 8w..8w+7, V rows 16w..16w+15 ----
  auto STAGE = [&](int sel, int kb) {
    const char* kgp = (const char*)Kg + (size_t)kb * 256;
    const char* vgp = (const char*)Vg + (size_t)kb * 2;
    char* kl = (char*)&KT[sel][0] + (8 * w) * 256;
    char* vl = (char*)&VT[sel][0] + (16 * w) * 128;
#pragma unroll
    for (int j = 0; j < 2; ++j) {
      int krow = 8 * w + 4 * j + (lane >> 4);
      int kcol = ((lane & 15) << 4) ^ ((((lane >> 4) + 4 * j) & 7) << 4);
      gload_lds16(kgp + (size_t)krow * 256 + kcol, kl + j * 1024);
      int vrow = 16 * w + 8 * j + (lane >> 3);
      int vcol = ((lane & 7) << 4) ^ (((lane >> 3) & 7) << 4);
      gload_lds16(vgp + (size_t)vrow * 8192 + vcol, vl + j * 1024);
    }
  };

  // ---- Q fragments: B-frag of swapped QK^T ----
  s16x8 aq[4];
#pragma unroll
  for (int kt = 0; kt < 4; ++kt)
    aq[kt] = *(const s16x8*)(Qb + bo + (size_t)(q0 + 16 * rg + l15) * H_ +
                             kt * 32 + quad * 8);

  f32x4 oacc[8];
#pragma unroll
  for (int nt = 0; nt < 8; ++nt) oacc[nt] = (f32x4){0.f, 0.f, 0.f, 0.f};
  float m15 = -3.0e38f;              // running max for q = l15
  float mT[4];                       // running max for q = quad*4+r
  float l15acc = 0.f;                // partial l (this lane's keys), q = l15
#pragma unroll
  for (int r = 0; r < 4; ++r) mT[r] = -3.0e38f;

  const int swr = (l15 & 7) << 4;    // read-side swizzle
  const int q4 = quad * 4;

  int cur = 0;
  if (i0 < i1) STAGE(0, i0 * 64);
  for (int i = i0; i < i1; ++i) {
    __syncthreads();  // buf[cur] staged (drains vmcnt) + WAR guard
    if (i + 1 < i1) STAGE(cur ^ 1, (i + 1) * 64);

    const char* Kl = (const char*)&KT[cur][0];
    const char* Vl = (const char*)&VT[cur][0];

    // S^T tiles: sc[nt] rows = keys kh*32+nt*16+quad*4+r, col = q = l15
    f32x4 sc[2];
#pragma unroll
    for (int nt = 0; nt < 2; ++nt) {
      f32x4 a = (f32x4){0.f, 0.f, 0.f, 0.f};
      const int krow = kh * 32 + nt * 16 + l15;
#pragma unroll
      for (int kt = 0; kt < 4; ++kt) {
        const s16x8 kf = *(const s16x8*)(Kl + krow * 256 +
                                         ((kt * 64 + quad * 16) ^ swr));
        a = __builtin_amdgcn_mfma_f32_16x16x32_bf16(kf, aq[kt], a, 0, 0, 0);
      }
      sc[nt] = a;
    }

    if (i == nk - 1) {  // diagonal tile: causal mask, key_local > q_local
      const int qrow = 16 * rg + l15;
#pragma unroll
      for (int nt = 0; nt < 2; ++nt)
#pragma unroll
        for (int r = 0; r < 4; ++r)
          if (kh * 32 + nt * 16 + q4 + r > qrow) sc[nt][r] = -3.0e38f;
    }

    // per-lane max over this wave's 8 keys, then cross-quad (xor 16/32)
    float vm = fmaxf(fmaxf(fmaxf(sc[0][0], sc[0][1]), fmaxf(sc[0][2], sc[0][3])),
                     fmaxf(fmaxf(sc[1][0], sc[1][1]), fmaxf(sc[1][2], sc[1][3])));
    vm = fmaxf(vm, __shfl_xor(vm, 16));
    vm = fmaxf(vm, __shfl_xor(vm, 32));
    const int par = i & 1;
    if (lane < 16) mx[par][w][lane] = vm;
    __asm__ volatile("s_waitcnt lgkmcnt(0)" ::: "memory");
    // raw barrier (staging vmcnt stays in flight); "memory" clobber stops
    // the compiler from hoisting the partner-mx read above it
    __asm__ volatile("s_barrier" ::: "memory");

    // merged tile max for q=l15 (P path) and q=quad*4+r (rescale path)
    float tile_m = fmaxf(vm, mx[par][w ^ 4][l15]);
    float mn = fmaxf(m15, tile_m);
    float al15 = exp2f((m15 - mn) * L2E);
    m15 = mn;
    float alT[4];
#pragma unroll
    for (int r = 0; r < 4; ++r) {
      float a2 = fmaxf(mx[par][w][q4 + r], mx[par][w ^ 4][q4 + r]);
      float mnT = fmaxf(mT[r], a2);
      alT[r] = exp2f((mT[r] - mnT) * L2E);
      mT[r] = mnT;
    }

    // P in-register -> PV A-frags (K=16): ap[nt][r] = P[q=l15][key q4+r]
    s16x4 ap[2];
    float lpart = 0.f;
#pragma unroll
    for (int nt = 0; nt < 2; ++nt)
#pragma unroll
      for (int r = 0; r < 4; ++r) {
        float pv = exp2f((sc[nt][r] - m15) * L2E);
        lpart += pv;
        ap[nt][r] = f2bf(pv);
      }
    l15acc = l15acc * al15 + lpart;

    // rescale O (rows q = quad*4+r)
#pragma unroll
    for (int ht = 0; ht < 8; ++ht)
#pragma unroll
      for (int r = 0; r < 4; ++r) oacc[ht][r] *= alT[r];

    // O += P @ V : B-frag = V[key=q4+j][h=ht*16+l15] from swizzled LDS
#pragma unroll
    for (int ht = 0; ht < 8; ++ht) {
#pragma unroll
      for (int nt = 0; nt < 2; ++nt) {
        const s16x4 vf = *(const s16x4*)(Vl + (ht * 16 + l15) * 128 +
                                         ((kh * 64 + nt * 32 + quad * 8) ^ swr));
        oacc[ht] = mfma16x16x16(ap[nt], vf, oacc[ht]);
      }
    }

    cur ^= 1;
  }

  // ---- epilogue: l reduce, kh-merge via dead KT, partial write + (m,l) ----
  float lw = l15acc;
  lw += __shfl_xor(lw, 16);
  lw += __shfl_xor(lw, 32);
  if (lane < 16) lx[w][lane] = lw;
  __syncthreads();  // all waves done with KT/VT; lx visible

  float* Ob = (float*)&KT[0][0];  // 32KB: [rg][16 rows][128 cols], KT dead
  if (kh == 1) {
#pragma unroll
    for (int ht = 0; ht < 8; ++ht)
#pragma unroll
      for (int r = 0; r < 4; ++r)
        Ob[rg * 2048 + (q4 + r) * 128 + ht * 16 + l15] = oacc[ht][r];
  }
  __syncthreads();
  if (kh == 0) {
    float* Od = half ? O1 : O0;
    // per-row (m, l): one lane per row writes
    if (l15 == 0) {
#pragma unroll
      for (int r = 0; r < 4; ++r) {
        int row = q0 + 16 * rg + q4 + r;
        float* mlp = ML + ((size_t)half * (B_ * S_) + b * S_ + row) * 2;
        mlp[0] = mT[r];
        mlp[1] = lx[w][q4 + r] + lx[w ^ 4][q4 + r];
      }
    }
#pragma unroll
    for (int ht = 0; ht < 8; ++ht)
#pragma unroll
      for (int r = 0; r < 4; ++r) {
        float o = oacc[ht][r] + Ob[rg * 2048 + (q4 + r) * 128 + ht * 16 + l15];
        Od[bo + (size_t)(q0 + 16 * rg + q4 + r) * H_ + ht * 16 + l15] = o;
      }
  }
}

// ---------------------------------------------------------------------------
// Kernel 4: merge the two split-K halves.
// out = (e1*O0 + e2*O1) / (e1*l1 + e2*l2), e = exp2((m - M)*L2E), M = max.
// Empty half (m=-3e38, l=0, O=0) -> e=0, exact no-op contribution.
// ---------------------------------------------------------------------------
__global__ __launch_bounds__(256) void merge_halves(
    float* __restrict__ O0, const float* __restrict__ O1,
    const float* __restrict__ ML) {
  const float L2E = 1.4426950408889634f;
  const int total = B_ * S_ * H_;
  int idx = (int)blockIdx.x * 256 + (int)threadIdx.x;
  for (; idx < total; idx += (int)gridDim.x * 256) {
    int brow = idx >> 7;  // b*S + s
    float m1 = ML[(size_t)brow * 2];
    float l1 = ML[(size_t)brow * 2 + 1];
    float m2 = ML[((size_t)(B_ * S_) + brow) * 2];
    float l2 = ML[((size_t)(B_ * S_) + brow) * 2 + 1];
    float M = fmaxf(m1, m2);
    float e1 = exp2f((m1 - M) * L2E);
    float e2 = exp2f((m2 - M) * L2E);
    float denom = e1 * l1 + e2 * l2;
    O0[idx] = (e1 * O0[idx] + e2 * O1[idx]) / denom;
  }
}

// ---------------------------------------------------------------------------
extern "C" void kernel_launch(void* const* d_in, const int* in_sizes, int n_in,
                              void* d_out, int out_size, void* d_ws, size_t ws_size,
                              hipStream_t stream) {
  const float* x  = (const float*)d_in[0];
  const float* Wq = (const float*)d_in[1];
  const float* bq = (const float*)d_in[2];
  const float* Wk = (const float*)d_in[3];
  const float* bk = (const float*)d_in[4];
  const float* Wv = (const float*)d_in[5];
  const float* bv = (const float*)d_in[6];

  // ws: Wt(1.5MB) | Q | K | Vt (4.2MB each, bf16) | O1 (8.4MB f32) | ML (256KB)
  short* Wt = (short*)d_ws;
  short* Q  = Wt + (size_t)384 * E_;
  short* K  = Q + (size_t)B_ * S_ * H_;
  short* Vt = K + (size_t)B_ * S_ * H_;
  float* O1 = (float*)(Vt + (size_t)B_ * S_ * H_);
  float* ML = O1 + (size_t)B_ * S_ * H_;
  float* out = (float*)d_out;

  hipLaunchKernelGGL(prep_weights, dim3(64 * 4, 3), dim3(256), 0, stream,
                     Wq, Wk, Wv, Wt);
  hipLaunchKernelGGL(qkv_gemm, dim3((B_ * S_) / 32 * 2), dim3(256), 0, stream,
                     x, Wt, bq, bk, bv, Q, K, Vt);
  // 512 blocks = 64 q-tiles x 4 batches x 2 split-K halves, heavy-first,
  // 2 blocks/CU co-resident (LDS 2x67KB).
  hipLaunchKernelGGL(flash_attn, dim3(64 * B_ * 2), dim3(512), 0, stream,
                     Q, K, Vt, out, O1, ML);
  hipLaunchKernelGGL(merge_halves, dim3(2048), dim3(256), 0, stream,
                     out, O1, ML);
}